// Round 7
// baseline (295.321 us; speedup 1.0000x reference)
//
#include <hip/hip_runtime.h>
#include <math.h>

// ---------------------------------------------------------------------------
// CNE: 2-layer GCN (PyG GCNConv norm w/ self loops) + outcome/propensity heads
// N=100000, E=1600000, IN=128, H=64, T=C=20000.
//
// R7: plane-split aggregation. G stored as [2][N][32] fp16 planes (6.4MB
// each); agg runs as two dispatches per layer, each gathering one plane,
// so the per-dispatch working set better fits the 4MiB per-XCD L2.
// xZ1 is planar fp16 too (gemm2 A-loads take plane stride). R6 otherwise.
// ---------------------------------------------------------------------------

#define CHUNK 16384  // edges per binning block
#define BSH 7        // 128 dst nodes per bucket

typedef __attribute__((ext_vector_type(8))) _Float16 half8;
typedef __attribute__((ext_vector_type(2))) _Float16 half2v;
typedef __attribute__((ext_vector_type(4))) float f32x4;

__device__ __forceinline__ float lrelu(float x) { return x > 0.0f ? x : 0.01f * x; }

__device__ __forceinline__ float wave_sum64(float v) {
#pragma unroll
  for (int m = 32; m >= 1; m >>= 1) v += __shfl_xor(v, m, 64);
  return v;
}

// ---- bucket histogram per chunk (LDS only) ----
__global__ void k_count(const int* __restrict__ dst, int E, int nbuck,
                        int* __restrict__ bcount, int* __restrict__ blkcount) {
  __shared__ int bh[1024];
  int t = threadIdx.x;
  for (int i = t; i < nbuck; i += 256) bh[i] = 0;
  __syncthreads();
  int e0 = blockIdx.x * CHUNK;
  int e1 = min(e0 + CHUNK, E);
  for (int e = e0 + t; e < e1; e += 256) atomicAdd(&bh[dst[e] >> BSH], 1);
  __syncthreads();
  for (int i = t; i < nbuck; i += 256) {
    int c = bh[i];
    blkcount[blockIdx.x * nbuck + i] = c;
    if (c) atomicAdd(&bcount[i], c);
  }
}

// ---- exclusive scan of bucket counts (nbuck <= 1024), one block ----
__global__ void k_scan1(const int* __restrict__ bcount, int* __restrict__ bbase, int nbuck) {
  __shared__ int s[1024];
  int t = threadIdx.x;
  int v = (t < nbuck) ? bcount[t] : 0;
  s[t] = v;
  __syncthreads();
  for (int off = 1; off < 1024; off <<= 1) {
    int u = (t >= off) ? s[t - off] : 0;
    __syncthreads();
    s[t] += u;
    __syncthreads();
  }
  if (t < nbuck) bbase[t] = s[t] - v;
}

// ---- per-(block,bucket) offsets: column scan over nblk entries ----
__global__ void k_scan2(const int* __restrict__ blkcount, const int* __restrict__ bbase,
                        int* __restrict__ blkoff, int nblk, int nbuck) {
  int lane = threadIdx.x & 63;
  int b = (blockIdx.x * blockDim.x + threadIdx.x) >> 6;  // one wave per bucket
  if (b >= nbuck) return;
  int carry = bbase[b];
  for (int base = 0; base < nblk; base += 64) {
    int i = base + lane;
    int v = (i < nblk) ? blkcount[i * nbuck + b] : 0;
    int x = v;
#pragma unroll
    for (int off = 1; off < 64; off <<= 1) {
      int u = __shfl_up(x, off, 64);
      if (lane >= off) x += u;
    }
    if (i < nblk) blkoff[i * nbuck + b] = carry + (x - v);
    carry += __shfl(x, 63, 64);
  }
}

// ---- binned scatter: pack src (bits 0..19) | (dst & 127) << 20 ----
__global__ void k_bscatter(const int* __restrict__ src, const int* __restrict__ dst,
                           int E, int nbuck, const int* __restrict__ blkoff,
                           unsigned int* __restrict__ pairs) {
  __shared__ int cur[1024];
  int t = threadIdx.x;
  for (int i = t; i < nbuck; i += 256) cur[i] = blkoff[blockIdx.x * nbuck + i];
  __syncthreads();
  int e0 = blockIdx.x * CHUNK;
  int e1 = min(e0 + CHUNK, E);
  for (int e = e0 + t; e < e1; e += 256) {
    int s = src[e];
    int d = dst[e];
    int p = atomicAdd(&cur[d >> BSH], 1);
    pairs[p] = (unsigned int)s | ((unsigned int)(d & 127) << 20);
  }
}

// ---- in-bucket sort -> per-node CSR + degree + dinv ----
__global__ void k_sort(const unsigned int* __restrict__ pairs, const int* __restrict__ bbase,
                       const int* __restrict__ bcount, int* __restrict__ slot,
                       int* __restrict__ offs, int* __restrict__ cntout,
                       float* __restrict__ dinv, int N) {
  __shared__ int hist[128];
  __shared__ int loc[128];
  __shared__ int cur[128];
  int b = blockIdx.x, t = threadIdx.x;
  if (t < 128) hist[t] = 0;
  __syncthreads();
  int start = bbase[b], cnt = bcount[b];
  for (int i = t; i < cnt; i += 256) atomicAdd(&hist[pairs[start + i] >> 20], 1);
  __syncthreads();
  if (t < 128) loc[t] = hist[t];
  __syncthreads();
  for (int off = 1; off < 128; off <<= 1) {
    int u = (t >= off && t < 128) ? loc[t - off] : 0;
    __syncthreads();
    if (t < 128) loc[t] += u;
    __syncthreads();
  }
  if (t < 128) {
    int ex = loc[t] - hist[t];  // exclusive scan
    cur[t] = ex;
    int node = (b << BSH) + t;
    if (node < N) {
      offs[node] = start + ex;
      cntout[node] = hist[t];
      dinv[node] = rsqrtf((float)(hist[t] + 1));
    }
  }
  __syncthreads();
  for (int i = t; i < cnt; i += 256) {
    unsigned int p = pairs[start + i];
    int d = (int)(p >> 20);
    int pos = atomicAdd(&cur[d], 1);
    slot[start + pos] = (int)(p & 0xFFFFFu);
  }
}

// ---- MFMA GEMM: G(planes) = fp16( dinv * (X @ W) ), W:[K,64] f32 ----
// Output planes: G[p][N][32], p = col>>5. APLANAR: X is [2][N][32] fp16.
template <int K, typename TIN, bool APLANAR>
__launch_bounds__(256)
__global__ void k_gemm_mfma(const TIN* __restrict__ X, const float* __restrict__ W,
                            const float* __restrict__ dinv, _Float16* __restrict__ G,
                            int N) {
  constexpr int KST = K / 32;
  const size_t planeE = (size_t)N * 32;
  int lane = threadIdx.x & 63;
  int wv = threadIdx.x >> 6;
  int lo = lane & 15;   // A row / B,D col (within tile)
  int hi = lane >> 4;   // k-group for A/B; row-group for D

  half8 bfrag[KST][4];
#pragma unroll
  for (int ks = 0; ks < KST; ks++)
#pragma unroll
    for (int ct = 0; ct < 4; ct++)
#pragma unroll
      for (int j = 0; j < 8; j++)
        bfrag[ks][ct][j] = (_Float16)W[(ks * 32 + hi * 8 + j) * 64 + ct * 16 + lo];

  int r0 = (blockIdx.x * 4 + wv) * 16;
  if (r0 >= N) return;

  f32x4 acc[4];
#pragma unroll
  for (int ct = 0; ct < 4; ct++)
#pragma unroll
    for (int j = 0; j < 4; j++) acc[ct][j] = 0.0f;

  int ar = min(r0 + lo, N - 1);
#pragma unroll
  for (int ks = 0; ks < KST; ks++) {
    half8 a;
    if constexpr (APLANAR) {
      a = *(const half8*)((const _Float16*)X + (size_t)ks * planeE + (size_t)ar * 32 + hi * 8);
    } else if constexpr (sizeof(TIN) == 4) {
      const float4* p = (const float4*)(X + (size_t)ar * K + ks * 32 + hi * 8);
      float4 u = p[0], v = p[1];
      a[0] = (_Float16)u.x; a[1] = (_Float16)u.y; a[2] = (_Float16)u.z; a[3] = (_Float16)u.w;
      a[4] = (_Float16)v.x; a[5] = (_Float16)v.y; a[6] = (_Float16)v.z; a[7] = (_Float16)v.w;
    } else {
      a = *(const half8*)(X + (size_t)ar * K + ks * 32 + hi * 8);
    }
#pragma unroll
    for (int ct = 0; ct < 4; ct++)
      acc[ct] = __builtin_amdgcn_mfma_f32_16x16x32_f16(a, bfrag[ks][ct], acc[ct], 0, 0, 0);
  }

  float dv[4];
#pragma unroll
  for (int j = 0; j < 4; j++) dv[j] = dinv[min(r0 + hi * 4 + j, N - 1)];
#pragma unroll
  for (int j = 0; j < 4; j++) {
    int rr = r0 + hi * 4 + j;
    if (rr < N) {
#pragma unroll
      for (int ct = 0; ct < 4; ct++) {
        _Float16* dst = G + (size_t)(ct >> 1) * planeE + (size_t)rr * 32 + (ct & 1) * 16 + lo;
        *dst = (_Float16)(acc[ct][j] * dv[j]);
      }
    }
  }
}

// ---- plane aggregation: wave per node, 16-lane sub-waves, 4 edges/inst ----
// Out[r, 2c2..2c2+1] = act(bias + dinv[r]*(Gp[r] + sum_nbr Gp[src]))
template <typename TOUT>
__launch_bounds__(256)
__global__ void k_aggp(const _Float16* __restrict__ Gp, const int* __restrict__ offs,
                       const int* __restrict__ count, const int* __restrict__ slot,
                       const float* __restrict__ dinv, const float* __restrict__ bias,
                       TOUT* __restrict__ OutBase, int rowstride, int N, int do_relu) {
  int lane = threadIdx.x & 63;
  int wid = (blockIdx.x * blockDim.x + threadIdx.x) >> 6;
  if (wid >= N) return;
  int r = __builtin_amdgcn_readfirstlane(wid);
  int es = lane >> 4;   // edge slot 0..3
  int c2 = lane & 15;   // col pair (cols 2c2, 2c2+1 of this plane)
  int start = offs[r], cnt = count[r];
  const _Float16* gp = Gp + 2 * c2;

  float sx = 0.f, sy = 0.f;
  if (es == 0) {  // self row
    half2v v = *(const half2v*)(gp + (size_t)r * 32);
    sx += (float)v[0]; sy += (float)v[1];
  }
  for (int j = 0; j < cnt; j += 16) {
    half2v v[4];
    bool a[4];
#pragma unroll
    for (int u = 0; u < 4; u++) {
      int idx = j + 4 * u + es;
      a[u] = idx < cnt;
      int e = slot[start + min(idx, cnt - 1)];
      v[u] = *(const half2v*)(gp + (size_t)e * 32);
    }
#pragma unroll
    for (int u = 0; u < 4; u++) {
      if (a[u]) { sx += (float)v[u][0]; sy += (float)v[u][1]; }
    }
  }
  sx += __shfl_xor(sx, 16, 64); sx += __shfl_xor(sx, 32, 64);
  sy += __shfl_xor(sy, 16, 64); sy += __shfl_xor(sy, 32, 64);

  if (lane < 16) {
    float d = dinv[r];
    float vx = bias[2 * c2] + d * sx;
    float vy = bias[2 * c2 + 1] + d * sy;
    if (do_relu) { vx = fmaxf(vx, 0.f); vy = fmaxf(vy, 0.f); }
    if constexpr (sizeof(TOUT) == 2) {
      half2v o; o[0] = (_Float16)vx; o[1] = (_Float16)vy;
      *(half2v*)((_Float16*)OutBase + (size_t)r * rowstride + 2 * c2) = o;
    } else {
      *(float2*)((float*)OutBase + (size_t)r * rowstride + 2 * c2) = make_float2(vx, vy);
    }
  }
}

// ---- propensity head via MFMA: tprob = lrelu(lrelu(Z@Wp1+bp1)@Wp2+bp2) ----
__launch_bounds__(256)
__global__ void k_tprob_mfma(const float* __restrict__ Z, const float* __restrict__ Wp1,
                             const float* __restrict__ bp1, const float* __restrict__ Wp2,
                             const float* __restrict__ bp2, float* __restrict__ tprob, int N) {
  int lane = threadIdx.x & 63;
  int wv = threadIdx.x >> 6;
  int lo = lane & 15;
  int hi = lane >> 4;

  half8 bfrag[2][4];
#pragma unroll
  for (int ks = 0; ks < 2; ks++)
#pragma unroll
    for (int ct = 0; ct < 4; ct++)
#pragma unroll
      for (int j = 0; j < 8; j++)
        bfrag[ks][ct][j] = (_Float16)Wp1[(ks * 32 + hi * 8 + j) * 64 + ct * 16 + lo];

  int r0 = (blockIdx.x * 4 + wv) * 16;
  if (r0 >= N) return;

  f32x4 acc[4];
#pragma unroll
  for (int ct = 0; ct < 4; ct++)
#pragma unroll
    for (int j = 0; j < 4; j++) acc[ct][j] = 0.0f;

  int ar = min(r0 + lo, N - 1);
#pragma unroll
  for (int ks = 0; ks < 2; ks++) {
    const float4* p = (const float4*)(Z + (size_t)ar * 64 + ks * 32 + hi * 8);
    float4 u = p[0], v = p[1];
    half8 a;
    a[0] = (_Float16)u.x; a[1] = (_Float16)u.y; a[2] = (_Float16)u.z; a[3] = (_Float16)u.w;
    a[4] = (_Float16)v.x; a[5] = (_Float16)v.y; a[6] = (_Float16)v.z; a[7] = (_Float16)v.w;
#pragma unroll
    for (int ct = 0; ct < 4; ct++)
      acc[ct] = __builtin_amdgcn_mfma_f32_16x16x32_f16(a, bfrag[ks][ct], acc[ct], 0, 0, 0);
  }

  float w20[4], w21[4], b1v[4];
#pragma unroll
  for (int ct = 0; ct < 4; ct++) {
    int col = ct * 16 + lo;
    w20[ct] = Wp2[col * 2 + 0];
    w21[ct] = Wp2[col * 2 + 1];
    b1v[ct] = bp1[col];
  }
  float b20 = bp2[0], b21 = bp2[1];

#pragma unroll
  for (int j = 0; j < 4; j++) {
    float t0 = 0.f, t1 = 0.f;
#pragma unroll
    for (int ct = 0; ct < 4; ct++) {
      float h = lrelu(acc[ct][j] + b1v[ct]);
      t0 = fmaf(h, w20[ct], t0);
      t1 = fmaf(h, w21[ct], t1);
    }
#pragma unroll
    for (int m = 1; m <= 8; m <<= 1) {
      t0 += __shfl_xor(t0, m, 64);
      t1 += __shfl_xor(t1, m, 64);
    }
    int rr = r0 + hi * 4 + j;
    if (lo == 0 && rr < N) {
      tprob[(size_t)rr * 2 + 0] = lrelu(t0 + b20);
      tprob[(size_t)rr * 2 + 1] = lrelu(t1 + b21);
    }
  }
}

// ---- outcome heads ----
__global__ void k_heads(const float* __restrict__ Z, const int* __restrict__ treat,
                        const int* __restrict__ ctrl, int T, int C,
                        const float* __restrict__ Wy1, const float* __restrict__ by1,
                        const float* __restrict__ Wy0, const float* __restrict__ by0,
                        float* __restrict__ y1, float* __restrict__ yc0,
                        float* __restrict__ y0, float* __restrict__ yc1) {
  int lane = threadIdx.x & 63;
  int wid = (blockIdx.x * blockDim.x + threadIdx.x) >> 6;
  if (wid >= T + C) return;
  bool treated = wid < T;
  int idx = treated ? wid : wid - T;
  int row = treated ? treat[idx] : ctrl[idx];
  row = __builtin_amdgcn_readfirstlane(row);
  float v = Z[(size_t)row * 64 + lane];
  float s1 = wave_sum64(v * Wy1[lane]);
  float s0 = wave_sum64(v * Wy0[lane]);
  if (lane == 0) {
    float a1 = lrelu(s1 + by1[0]);
    float a0 = lrelu(s0 + by0[0]);
    if (treated) { y1[idx] = a1; yc0[idx] = a0; }
    else         { yc1[idx] = a1; y0[idx] = a0; }
  }
}

extern "C" void kernel_launch(void* const* d_in, const int* in_sizes, int n_in,
                              void* d_out, int out_size, void* d_ws, size_t ws_size,
                              hipStream_t stream) {
  const int IN = 128, H = 64;
  const int N = in_sizes[0] / IN;
  const int E = in_sizes[1] / 2;
  const int T = in_sizes[2];
  const int C = in_sizes[3];
  const int nbuck = (N + 127) >> BSH;         // 782
  const int nblk = (E + CHUNK - 1) / CHUNK;   // 98
  const size_t planeE = (size_t)N * 32;

  const float* x    = (const float*)d_in[0];
  const int*   ei   = (const int*)d_in[1];
  const int*   src  = ei;
  const int*   dst  = ei + E;
  const int*   trt  = (const int*)d_in[2];
  const int*   ctl  = (const int*)d_in[3];
  const float* W1   = (const float*)d_in[4];
  const float* b1   = (const float*)d_in[5];
  const float* W2   = (const float*)d_in[6];
  const float* b2   = (const float*)d_in[7];
  const float* Wy1  = (const float*)d_in[8];
  const float* by1  = (const float*)d_in[9];
  const float* Wy0  = (const float*)d_in[10];
  const float* by0  = (const float*)d_in[11];
  const float* Wp1  = (const float*)d_in[12];
  const float* bp1  = (const float*)d_in[13];
  const float* Wp2  = (const float*)d_in[14];
  const float* bp2  = (const float*)d_in[15];

  float* out   = (float*)d_out;
  float* y1    = out;                          // [T]
  float* yc0   = out + T;                      // [T]
  float* y0    = out + 2 * T;                  // [C]
  float* yc1   = out + 2 * T + C;              // [C]
  float* tprob = out + 2 * T + 2 * C;          // [N,2]
  float* xZ2   = out + 2 * T + 2 * C + 2 * N;  // [N,64]

  // workspace layout (4-byte units)
  int* bcount    = (int*)d_ws;                      // 1024 (zeroed)
  int* bbase     = bcount + 1024;                   // 1024
  int* blkcount  = bbase + 1024;                    // nblk*nbuck
  int* blkoff    = blkcount + (size_t)nblk * nbuck; // nblk*nbuck
  unsigned int* pairs = (unsigned int*)(blkoff + (size_t)nblk * nbuck);  // E
  int* slot      = (int*)(pairs + E);               // E
  int* offs      = slot + E;                        // N
  int* cnt       = offs + N;                        // N
  float* dinv    = (float*)(cnt + N);               // N
  size_t goff = ((size_t)(dinv + N - (float*)d_ws) + 3) & ~(size_t)3;
  _Float16* g16 = (_Float16*)((float*)d_ws + goff);     // 2 planes * N*32
  _Float16* xZ1 = g16 + 2 * planeE;                     // 2 planes * N*32

  hipMemsetAsync(bcount, 0, sizeof(int) * 1024, stream);

  k_count<<<nblk, 256, 0, stream>>>(dst, E, nbuck, bcount, blkcount);
  k_scan1<<<1, 1024, 0, stream>>>(bcount, bbase, nbuck);
  k_scan2<<<(nbuck * 64 + 255) / 256, 256, 0, stream>>>(blkcount, bbase, blkoff, nblk, nbuck);
  k_bscatter<<<nblk, 256, 0, stream>>>(src, dst, E, nbuck, blkoff, pairs);
  k_sort<<<nbuck, 256, 0, stream>>>(pairs, bbase, bcount, slot, offs, cnt, dinv, N);

  const int ngemm = (N + 63) / 64;
  const int nagg = (int)(((size_t)N * 64 + 255) / 256);

  // layer 1: g16 planes = fp16(dinv*(x@W1)); xZ1 planes = relu(...)
  k_gemm_mfma<128, float, false><<<ngemm, 256, 0, stream>>>(x, W1, dinv, g16, N);
  k_aggp<_Float16><<<nagg, 256, 0, stream>>>(g16, offs, cnt, slot, dinv, b1,
                                             xZ1, 32, N, 1);
  k_aggp<_Float16><<<nagg, 256, 0, stream>>>(g16 + planeE, offs, cnt, slot, dinv, b1 + 32,
                                             xZ1 + planeE, 32, N, 1);

  // layer 2: g16 planes = fp16(dinv*(xZ1@W2)); xZ2 = b2 + dinv*(...) (fp32)
  k_gemm_mfma<64, _Float16, true><<<ngemm, 256, 0, stream>>>(xZ1, W2, dinv, g16, N);
  k_aggp<float><<<nagg, 256, 0, stream>>>(g16, offs, cnt, slot, dinv, b2,
                                          xZ2, 64, N, 0);
  k_aggp<float><<<nagg, 256, 0, stream>>>(g16 + planeE, offs, cnt, slot, dinv, b2 + 32,
                                          xZ2 + 32, 64, N, 0);

  // heads
  k_tprob_mfma<<<ngemm, 256, 0, stream>>>(xZ2, Wp1, bp1, Wp2, bp2, tprob, N);
  k_heads<<<((size_t)(T + C) * 64 + 255) / 256, 256, 0, stream>>>(
      xZ2, trt, ctl, T, C, Wy1, by1, Wy0, by0, y1, yc0, y0, yc1);
}

// Round 8
// 247.205 us; speedup vs baseline: 1.1946x; 1.1946x over previous
//
#include <hip/hip_runtime.h>
#include <math.h>

// ---------------------------------------------------------------------------
// CNE: 2-layer GCN (PyG GCNConv norm w/ self loops) + outcome/propensity heads
// N=100000, E=1600000, IN=128, H=64, T=C=20000.
//
// R8: revert R7 plane split (proved: no hit-rate gain, halved per-wave MLP).
// Agg = R6 structure with 32-edge predicated window (32 rows in flight/wave).
// scan1+scan2 merged into one single-block kernel.
// ---------------------------------------------------------------------------

#define CHUNK 16384  // edges per binning block
#define BSH 7        // 128 dst nodes per bucket

typedef __attribute__((ext_vector_type(8))) _Float16 half8;
typedef __attribute__((ext_vector_type(2))) _Float16 half2v;
typedef __attribute__((ext_vector_type(4))) float f32x4;

__device__ __forceinline__ float lrelu(float x) { return x > 0.0f ? x : 0.01f * x; }

__device__ __forceinline__ float wave_sum64(float v) {
#pragma unroll
  for (int m = 32; m >= 1; m >>= 1) v += __shfl_xor(v, m, 64);
  return v;
}

// ---- bucket histogram per chunk (LDS only) ----
__global__ void k_count(const int* __restrict__ dst, int E, int nbuck,
                        int* __restrict__ bcount, int* __restrict__ blkcount) {
  __shared__ int bh[1024];
  int t = threadIdx.x;
  for (int i = t; i < nbuck; i += 256) bh[i] = 0;
  __syncthreads();
  int e0 = blockIdx.x * CHUNK;
  int e1 = min(e0 + CHUNK, E);
  for (int e = e0 + t; e < e1; e += 256) atomicAdd(&bh[dst[e] >> BSH], 1);
  __syncthreads();
  for (int i = t; i < nbuck; i += 256) {
    int c = bh[i];
    blkcount[blockIdx.x * nbuck + i] = c;
    if (c) atomicAdd(&bcount[i], c);
  }
}

// ---- merged scan: bucket-total exclusive scan + per-(block,bucket) offsets ----
// one block, 1024 threads; thread t owns bucket t.
__global__ void k_scan(const int* __restrict__ bcount, int* __restrict__ bbase,
                       const int* __restrict__ blkcount, int* __restrict__ blkoff,
                       int nbuck, int nblk) {
  __shared__ int s[1024];
  int t = threadIdx.x;
  int v = (t < nbuck) ? bcount[t] : 0;
  s[t] = v;
  __syncthreads();
  for (int off = 1; off < 1024; off <<= 1) {
    int u = (t >= off) ? s[t - off] : 0;
    __syncthreads();
    s[t] += u;
    __syncthreads();
  }
  if (t < nbuck) {
    int carry = s[t] - v;  // exclusive
    bbase[t] = carry;
    for (int i = 0; i < nblk; i++) {
      int c = blkcount[(size_t)i * nbuck + t];  // coalesced across t
      blkoff[(size_t)i * nbuck + t] = carry;
      carry += c;
    }
  }
}

// ---- binned scatter: pack src (bits 0..19) | (dst & 127) << 20 ----
__global__ void k_bscatter(const int* __restrict__ src, const int* __restrict__ dst,
                           int E, int nbuck, const int* __restrict__ blkoff,
                           unsigned int* __restrict__ pairs) {
  __shared__ int cur[1024];
  int t = threadIdx.x;
  for (int i = t; i < nbuck; i += 256) cur[i] = blkoff[blockIdx.x * nbuck + i];
  __syncthreads();
  int e0 = blockIdx.x * CHUNK;
  int e1 = min(e0 + CHUNK, E);
  for (int e = e0 + t; e < e1; e += 256) {
    int s = src[e];
    int d = dst[e];
    int p = atomicAdd(&cur[d >> BSH], 1);
    pairs[p] = (unsigned int)s | ((unsigned int)(d & 127) << 20);
  }
}

// ---- in-bucket sort -> per-node CSR + degree + dinv ----
__global__ void k_sort(const unsigned int* __restrict__ pairs, const int* __restrict__ bbase,
                       const int* __restrict__ bcount, int* __restrict__ slot,
                       int* __restrict__ offs, int* __restrict__ cntout,
                       float* __restrict__ dinv, int N) {
  __shared__ int hist[128];
  __shared__ int loc[128];
  __shared__ int cur[128];
  int b = blockIdx.x, t = threadIdx.x;
  if (t < 128) hist[t] = 0;
  __syncthreads();
  int start = bbase[b], cnt = bcount[b];
  for (int i = t; i < cnt; i += 256) atomicAdd(&hist[pairs[start + i] >> 20], 1);
  __syncthreads();
  if (t < 128) loc[t] = hist[t];
  __syncthreads();
  for (int off = 1; off < 128; off <<= 1) {
    int u = (t >= off && t < 128) ? loc[t - off] : 0;
    __syncthreads();
    if (t < 128) loc[t] += u;
    __syncthreads();
  }
  if (t < 128) {
    int ex = loc[t] - hist[t];  // exclusive scan
    cur[t] = ex;
    int node = (b << BSH) + t;
    if (node < N) {
      offs[node] = start + ex;
      cntout[node] = hist[t];
      dinv[node] = rsqrtf((float)(hist[t] + 1));
    }
  }
  __syncthreads();
  for (int i = t; i < cnt; i += 256) {
    unsigned int p = pairs[start + i];
    int d = (int)(p >> 20);
    int pos = atomicAdd(&cur[d], 1);
    slot[start + pos] = (int)(p & 0xFFFFFu);
  }
}

// ---- MFMA GEMM: G16 = fp16( dinv * (X @ W) ), X:[N,K] (TIN), W:[K,64] f32 ----
template <int K, typename TIN>
__launch_bounds__(256)
__global__ void k_gemm_mfma(const TIN* __restrict__ X, const float* __restrict__ W,
                            const float* __restrict__ dinv, _Float16* __restrict__ G, int N) {
  constexpr int KST = K / 32;
  int lane = threadIdx.x & 63;
  int wv = threadIdx.x >> 6;
  int lo = lane & 15;   // A row / B,D col (within tile)
  int hi = lane >> 4;   // k-group for A/B; row-group for D

  half8 bfrag[KST][4];
#pragma unroll
  for (int ks = 0; ks < KST; ks++)
#pragma unroll
    for (int ct = 0; ct < 4; ct++)
#pragma unroll
      for (int j = 0; j < 8; j++)
        bfrag[ks][ct][j] = (_Float16)W[(ks * 32 + hi * 8 + j) * 64 + ct * 16 + lo];

  int r0 = (blockIdx.x * 4 + wv) * 16;
  if (r0 >= N) return;

  f32x4 acc[4];
#pragma unroll
  for (int ct = 0; ct < 4; ct++)
#pragma unroll
    for (int j = 0; j < 4; j++) acc[ct][j] = 0.0f;

  int ar = min(r0 + lo, N - 1);
#pragma unroll
  for (int ks = 0; ks < KST; ks++) {
    const TIN* ap = X + (size_t)ar * K + ks * 32 + hi * 8;
    half8 a;
    if constexpr (sizeof(TIN) == 4) {
      const float4* p = (const float4*)ap;
      float4 u = p[0], v = p[1];
      a[0] = (_Float16)u.x; a[1] = (_Float16)u.y; a[2] = (_Float16)u.z; a[3] = (_Float16)u.w;
      a[4] = (_Float16)v.x; a[5] = (_Float16)v.y; a[6] = (_Float16)v.z; a[7] = (_Float16)v.w;
    } else {
      a = *(const half8*)ap;
    }
#pragma unroll
    for (int ct = 0; ct < 4; ct++)
      acc[ct] = __builtin_amdgcn_mfma_f32_16x16x32_f16(a, bfrag[ks][ct], acc[ct], 0, 0, 0);
  }

  float dv[4];
#pragma unroll
  for (int j = 0; j < 4; j++) dv[j] = dinv[min(r0 + hi * 4 + j, N - 1)];
#pragma unroll
  for (int j = 0; j < 4; j++) {
    int rr = r0 + hi * 4 + j;
    if (rr < N) {
#pragma unroll
      for (int ct = 0; ct < 4; ct++)
        G[(size_t)rr * 64 + ct * 16 + lo] = (_Float16)(acc[ct][j] * dv[j]);
    }
  }
}

// ---- aggregation: wave per node, half2/lane, 32-edge predicated window ----
// (16 loads = 32 G-rows in flight per wave per iteration)
template <typename TOUT>
__launch_bounds__(256)
__global__ void k_agg(const _Float16* __restrict__ G, const int* __restrict__ offs,
                      const int* __restrict__ count, const int* __restrict__ slot,
                      const float* __restrict__ dinv, const float* __restrict__ bias,
                      TOUT* __restrict__ Out, int N, int do_relu) {
  int lane = threadIdx.x & 63;
  int wid = (blockIdx.x * blockDim.x + threadIdx.x) >> 6;
  if (wid >= N) return;
  int r = __builtin_amdgcn_readfirstlane(wid);
  int cp = lane & 31;  // column pair: cols {2cp, 2cp+1}
  int rs = lane >> 5;  // row slot: even/odd edge
  int start = offs[r], cnt = count[r];
  const _Float16* gp = G + 2 * cp;

  float sx = 0.f, sy = 0.f;
  if (rs == 0) {  // self row once
    half2v v = *(const half2v*)(gp + (size_t)r * 64);
    sx += (float)v[0]; sy += (float)v[1];
  }
  for (int j = 0; j < cnt; j += 32) {
    half2v v[16];
    bool a[16];
#pragma unroll
    for (int u = 0; u < 16; u++) {
      int idx = j + 2 * u + rs;
      a[u] = idx < cnt;
      int e = slot[start + min(idx, cnt - 1)];
      v[u] = *(const half2v*)(gp + (size_t)e * 64);
    }
#pragma unroll
    for (int u = 0; u < 16; u++) {
      if (a[u]) { sx += (float)v[u][0]; sy += (float)v[u][1]; }
    }
  }
  // merge even/odd edge halves
  sx += __shfl_xor(sx, 32, 64);
  sy += __shfl_xor(sy, 32, 64);

  if (rs == 0) {
    float d = dinv[r];
    float vx = bias[2 * cp] + d * sx;
    float vy = bias[2 * cp + 1] + d * sy;
    if (do_relu) { vx = fmaxf(vx, 0.f); vy = fmaxf(vy, 0.f); }
    if constexpr (sizeof(TOUT) == 2) {
      half2v o; o[0] = (_Float16)vx; o[1] = (_Float16)vy;
      *(half2v*)((_Float16*)Out + (size_t)r * 64 + 2 * cp) = o;
    } else {
      *(float2*)((float*)Out + (size_t)r * 64 + 2 * cp) = make_float2(vx, vy);
    }
  }
}

// ---- propensity head via MFMA: tprob = lrelu(lrelu(Z@Wp1+bp1)@Wp2+bp2) ----
__launch_bounds__(256)
__global__ void k_tprob_mfma(const float* __restrict__ Z, const float* __restrict__ Wp1,
                             const float* __restrict__ bp1, const float* __restrict__ Wp2,
                             const float* __restrict__ bp2, float* __restrict__ tprob, int N) {
  int lane = threadIdx.x & 63;
  int wv = threadIdx.x >> 6;
  int lo = lane & 15;
  int hi = lane >> 4;

  half8 bfrag[2][4];
#pragma unroll
  for (int ks = 0; ks < 2; ks++)
#pragma unroll
    for (int ct = 0; ct < 4; ct++)
#pragma unroll
      for (int j = 0; j < 8; j++)
        bfrag[ks][ct][j] = (_Float16)Wp1[(ks * 32 + hi * 8 + j) * 64 + ct * 16 + lo];

  int r0 = (blockIdx.x * 4 + wv) * 16;
  if (r0 >= N) return;

  f32x4 acc[4];
#pragma unroll
  for (int ct = 0; ct < 4; ct++)
#pragma unroll
    for (int j = 0; j < 4; j++) acc[ct][j] = 0.0f;

  int ar = min(r0 + lo, N - 1);
#pragma unroll
  for (int ks = 0; ks < 2; ks++) {
    const float4* p = (const float4*)(Z + (size_t)ar * 64 + ks * 32 + hi * 8);
    float4 u = p[0], v = p[1];
    half8 a;
    a[0] = (_Float16)u.x; a[1] = (_Float16)u.y; a[2] = (_Float16)u.z; a[3] = (_Float16)u.w;
    a[4] = (_Float16)v.x; a[5] = (_Float16)v.y; a[6] = (_Float16)v.z; a[7] = (_Float16)v.w;
#pragma unroll
    for (int ct = 0; ct < 4; ct++)
      acc[ct] = __builtin_amdgcn_mfma_f32_16x16x32_f16(a, bfrag[ks][ct], acc[ct], 0, 0, 0);
  }

  float w20[4], w21[4], b1v[4];
#pragma unroll
  for (int ct = 0; ct < 4; ct++) {
    int col = ct * 16 + lo;
    w20[ct] = Wp2[col * 2 + 0];
    w21[ct] = Wp2[col * 2 + 1];
    b1v[ct] = bp1[col];
  }
  float b20 = bp2[0], b21 = bp2[1];

#pragma unroll
  for (int j = 0; j < 4; j++) {
    float t0 = 0.f, t1 = 0.f;
#pragma unroll
    for (int ct = 0; ct < 4; ct++) {
      float h = lrelu(acc[ct][j] + b1v[ct]);
      t0 = fmaf(h, w20[ct], t0);
      t1 = fmaf(h, w21[ct], t1);
    }
#pragma unroll
    for (int m = 1; m <= 8; m <<= 1) {
      t0 += __shfl_xor(t0, m, 64);
      t1 += __shfl_xor(t1, m, 64);
    }
    int rr = r0 + hi * 4 + j;
    if (lo == 0 && rr < N) {
      tprob[(size_t)rr * 2 + 0] = lrelu(t0 + b20);
      tprob[(size_t)rr * 2 + 1] = lrelu(t1 + b21);
    }
  }
}

// ---- outcome heads ----
__global__ void k_heads(const float* __restrict__ Z, const int* __restrict__ treat,
                        const int* __restrict__ ctrl, int T, int C,
                        const float* __restrict__ Wy1, const float* __restrict__ by1,
                        const float* __restrict__ Wy0, const float* __restrict__ by0,
                        float* __restrict__ y1, float* __restrict__ yc0,
                        float* __restrict__ y0, float* __restrict__ yc1) {
  int lane = threadIdx.x & 63;
  int wid = (blockIdx.x * blockDim.x + threadIdx.x) >> 6;
  if (wid >= T + C) return;
  bool treated = wid < T;
  int idx = treated ? wid : wid - T;
  int row = treated ? treat[idx] : ctrl[idx];
  row = __builtin_amdgcn_readfirstlane(row);
  float v = Z[(size_t)row * 64 + lane];
  float s1 = wave_sum64(v * Wy1[lane]);
  float s0 = wave_sum64(v * Wy0[lane]);
  if (lane == 0) {
    float a1 = lrelu(s1 + by1[0]);
    float a0 = lrelu(s0 + by0[0]);
    if (treated) { y1[idx] = a1; yc0[idx] = a0; }
    else         { yc1[idx] = a1; y0[idx] = a0; }
  }
}

extern "C" void kernel_launch(void* const* d_in, const int* in_sizes, int n_in,
                              void* d_out, int out_size, void* d_ws, size_t ws_size,
                              hipStream_t stream) {
  const int IN = 128, H = 64;
  const int N = in_sizes[0] / IN;
  const int E = in_sizes[1] / 2;
  const int T = in_sizes[2];
  const int C = in_sizes[3];
  const int nbuck = (N + 127) >> BSH;         // 782
  const int nblk = (E + CHUNK - 1) / CHUNK;   // 98

  const float* x    = (const float*)d_in[0];
  const int*   ei   = (const int*)d_in[1];
  const int*   src  = ei;
  const int*   dst  = ei + E;
  const int*   trt  = (const int*)d_in[2];
  const int*   ctl  = (const int*)d_in[3];
  const float* W1   = (const float*)d_in[4];
  const float* b1   = (const float*)d_in[5];
  const float* W2   = (const float*)d_in[6];
  const float* b2   = (const float*)d_in[7];
  const float* Wy1  = (const float*)d_in[8];
  const float* by1  = (const float*)d_in[9];
  const float* Wy0  = (const float*)d_in[10];
  const float* by0  = (const float*)d_in[11];
  const float* Wp1  = (const float*)d_in[12];
  const float* bp1  = (const float*)d_in[13];
  const float* Wp2  = (const float*)d_in[14];
  const float* bp2  = (const float*)d_in[15];

  float* out   = (float*)d_out;
  float* y1    = out;                          // [T]
  float* yc0   = out + T;                      // [T]
  float* y0    = out + 2 * T;                  // [C]
  float* yc1   = out + 2 * T + C;              // [C]
  float* tprob = out + 2 * T + 2 * C;          // [N,2]
  float* xZ2   = out + 2 * T + 2 * C + 2 * N;  // [N,64]

  // workspace layout (4-byte units)
  int* bcount    = (int*)d_ws;                      // 1024 (zeroed)
  int* bbase     = bcount + 1024;                   // 1024
  int* blkcount  = bbase + 1024;                    // nblk*nbuck
  int* blkoff    = blkcount + (size_t)nblk * nbuck; // nblk*nbuck
  unsigned int* pairs = (unsigned int*)(blkoff + (size_t)nblk * nbuck);  // E
  int* slot      = (int*)(pairs + E);               // E
  int* offs      = slot + E;                        // N
  int* cnt       = offs + N;                        // N
  float* dinv    = (float*)(cnt + N);               // N
  size_t goff = ((size_t)(dinv + N - (float*)d_ws) + 3) & ~(size_t)3;
  _Float16* g16 = (_Float16*)((float*)d_ws + goff);     // N*64 halves
  _Float16* xZ1 = g16 + (size_t)N * 64;                 // N*64 halves

  hipMemsetAsync(bcount, 0, sizeof(int) * 1024, stream);

  k_count<<<nblk, 256, 0, stream>>>(dst, E, nbuck, bcount, blkcount);
  k_scan<<<1, 1024, 0, stream>>>(bcount, bbase, blkcount, blkoff, nbuck, nblk);
  k_bscatter<<<nblk, 256, 0, stream>>>(src, dst, E, nbuck, blkoff, pairs);
  k_sort<<<nbuck, 256, 0, stream>>>(pairs, bbase, bcount, slot, offs, cnt, dinv, N);

  const int ngemm = (N + 63) / 64;
  const int nagg = (int)(((size_t)N * 64 + 255) / 256);

  // layer 1
  k_gemm_mfma<128, float><<<ngemm, 256, 0, stream>>>(x, W1, dinv, g16, N);
  k_agg<_Float16><<<nagg, 256, 0, stream>>>(g16, offs, cnt, slot, dinv, b1, xZ1, N, 1);

  // layer 2
  k_gemm_mfma<64, _Float16><<<ngemm, 256, 0, stream>>>(xZ1, W2, dinv, g16, N);
  k_agg<float><<<nagg, 256, 0, stream>>>(g16, offs, cnt, slot, dinv, b2, xZ2, N, 0);

  // heads
  k_tprob_mfma<<<ngemm, 256, 0, stream>>>(xZ2, Wp1, bp1, Wp2, bp2, tprob, N);
  k_heads<<<((size_t)(T + C) * 64 + 255) / 256, 256, 0, stream>>>(
      xZ2, trt, ctl, T, C, Wy1, by1, Wy0, by0, y1, yc0, y0, yc1);
}

// Round 9
// 204.282 us; speedup vs baseline: 1.4456x; 1.2101x over previous
//
#include <hip/hip_runtime.h>
#include <math.h>

// ---------------------------------------------------------------------------
// CNE: 2-layer GCN (PyG GCNConv norm w/ self loops) + outcome/propensity heads
// N=100000, E=1600000, IN=128, H=64, T=C=20000.
//
// R9: scan-free slab CSR build.
//  - k_bin: LDS bucket hist -> global atomicAdd range reservation in a
//    fixed-CAP slab -> scatter. (replaces k_count + scans + k_bscatter)
//  - k_sort: slab segment staged in LDS, per-node CSR built in-place.
//  - agg (32-edge window), MFMA GEMMs, tprob_mfma, heads unchanged (R8).
// ---------------------------------------------------------------------------

#define CHUNK 16384  // edges per binning block
#define BSH 7        // 128 dst nodes per bucket
#define CAP 3072     // slab capacity per bucket (mean 2046, max ~2250)

typedef __attribute__((ext_vector_type(8))) _Float16 half8;
typedef __attribute__((ext_vector_type(2))) _Float16 half2v;
typedef __attribute__((ext_vector_type(4))) float f32x4;

__device__ __forceinline__ float lrelu(float x) { return x > 0.0f ? x : 0.01f * x; }

__device__ __forceinline__ float wave_sum64(float v) {
#pragma unroll
  for (int m = 32; m >= 1; m >>= 1) v += __shfl_xor(v, m, 64);
  return v;
}

// ---- fused bin: LDS hist -> global range reservation -> slab scatter ----
__global__ void k_bin(const int* __restrict__ src, const int* __restrict__ dst,
                      int E, int nbuck, int* __restrict__ cur,
                      unsigned int* __restrict__ pairs) {
  __shared__ int bh[1024];  // per-bucket count, then per-bucket cursor
  __shared__ int bb[1024];  // per-bucket reserved base
  int t = threadIdx.x;
  for (int i = t; i < nbuck; i += 256) bh[i] = 0;
  __syncthreads();
  int e0 = blockIdx.x * CHUNK;
  int e1 = min(e0 + CHUNK, E);
  for (int e = e0 + t; e < e1; e += 256) atomicAdd(&bh[dst[e] >> BSH], 1);
  __syncthreads();
  for (int i = t; i < nbuck; i += 256) {
    int c = bh[i];
    bb[i] = c ? atomicAdd(&cur[i], c) : 0;
  }
  __syncthreads();
  for (int i = t; i < nbuck; i += 256) bh[i] = 0;  // reuse as intra-block cursor
  __syncthreads();
  for (int e = e0 + t; e < e1; e += 256) {
    int s = src[e];
    int d = dst[e];
    int b = d >> BSH;
    int p = atomicAdd(&bh[b], 1);
    pairs[(size_t)b * CAP + bb[b] + p] = (unsigned int)s | ((unsigned int)(d & 127) << 20);
  }
}

// ---- in-bucket sort (LDS-staged, in-place slab) -> per-node CSR + dinv ----
__global__ void k_sort(unsigned int* __restrict__ pairs, const int* __restrict__ cur,
                       int* __restrict__ offs, int* __restrict__ cntout,
                       float* __restrict__ dinv, int N) {
  __shared__ unsigned int seg[CAP];
  __shared__ int hist[128];
  __shared__ int loc[128];
  __shared__ int lcur[128];
  int b = blockIdx.x, t = threadIdx.x;
  int c = cur[b];
  size_t base = (size_t)b * CAP;
  for (int i = t; i < c; i += 256) seg[i] = pairs[base + i];
  if (t < 128) hist[t] = 0;
  __syncthreads();  // all global reads of this block's slab segment done
  for (int i = t; i < c; i += 256) atomicAdd(&hist[seg[i] >> 20], 1);
  __syncthreads();
  if (t < 128) loc[t] = hist[t];
  __syncthreads();
  for (int off = 1; off < 128; off <<= 1) {
    int u = (t >= off && t < 128) ? loc[t - off] : 0;
    __syncthreads();
    if (t < 128) loc[t] += u;
    __syncthreads();
  }
  if (t < 128) {
    int ex = loc[t] - hist[t];  // exclusive scan
    lcur[t] = ex;
    int node = (b << BSH) + t;
    if (node < N) {
      offs[node] = (int)base + ex;
      cntout[node] = hist[t];
      dinv[node] = rsqrtf((float)(hist[t] + 1));
    }
  }
  __syncthreads();
  for (int i = t; i < c; i += 256) {
    unsigned int p = seg[i];
    int d = (int)(p >> 20);
    int pos = atomicAdd(&lcur[d], 1);
    pairs[base + pos] = p & 0xFFFFFu;  // sorted src index (consumed as int)
  }
}

// ---- MFMA GEMM: G16 = fp16( dinv * (X @ W) ), X:[N,K] (TIN), W:[K,64] f32 ----
template <int K, typename TIN>
__launch_bounds__(256)
__global__ void k_gemm_mfma(const TIN* __restrict__ X, const float* __restrict__ W,
                            const float* __restrict__ dinv, _Float16* __restrict__ G, int N) {
  constexpr int KST = K / 32;
  int lane = threadIdx.x & 63;
  int wv = threadIdx.x >> 6;
  int lo = lane & 15;   // A row / B,D col (within tile)
  int hi = lane >> 4;   // k-group for A/B; row-group for D

  half8 bfrag[KST][4];
#pragma unroll
  for (int ks = 0; ks < KST; ks++)
#pragma unroll
    for (int ct = 0; ct < 4; ct++)
#pragma unroll
      for (int j = 0; j < 8; j++)
        bfrag[ks][ct][j] = (_Float16)W[(ks * 32 + hi * 8 + j) * 64 + ct * 16 + lo];

  int r0 = (blockIdx.x * 4 + wv) * 16;
  if (r0 >= N) return;

  f32x4 acc[4];
#pragma unroll
  for (int ct = 0; ct < 4; ct++)
#pragma unroll
    for (int j = 0; j < 4; j++) acc[ct][j] = 0.0f;

  int ar = min(r0 + lo, N - 1);
#pragma unroll
  for (int ks = 0; ks < KST; ks++) {
    const TIN* ap = X + (size_t)ar * K + ks * 32 + hi * 8;
    half8 a;
    if constexpr (sizeof(TIN) == 4) {
      const float4* p = (const float4*)ap;
      float4 u = p[0], v = p[1];
      a[0] = (_Float16)u.x; a[1] = (_Float16)u.y; a[2] = (_Float16)u.z; a[3] = (_Float16)u.w;
      a[4] = (_Float16)v.x; a[5] = (_Float16)v.y; a[6] = (_Float16)v.z; a[7] = (_Float16)v.w;
    } else {
      a = *(const half8*)ap;
    }
#pragma unroll
    for (int ct = 0; ct < 4; ct++)
      acc[ct] = __builtin_amdgcn_mfma_f32_16x16x32_f16(a, bfrag[ks][ct], acc[ct], 0, 0, 0);
  }

  float dv[4];
#pragma unroll
  for (int j = 0; j < 4; j++) dv[j] = dinv[min(r0 + hi * 4 + j, N - 1)];
#pragma unroll
  for (int j = 0; j < 4; j++) {
    int rr = r0 + hi * 4 + j;
    if (rr < N) {
#pragma unroll
      for (int ct = 0; ct < 4; ct++)
        G[(size_t)rr * 64 + ct * 16 + lo] = (_Float16)(acc[ct][j] * dv[j]);
    }
  }
}

// ---- aggregation: wave per node, half2/lane, 32-edge predicated window ----
template <typename TOUT>
__launch_bounds__(256)
__global__ void k_agg(const _Float16* __restrict__ G, const int* __restrict__ offs,
                      const int* __restrict__ count, const int* __restrict__ slot,
                      const float* __restrict__ dinv, const float* __restrict__ bias,
                      TOUT* __restrict__ Out, int N, int do_relu) {
  int lane = threadIdx.x & 63;
  int wid = (blockIdx.x * blockDim.x + threadIdx.x) >> 6;
  if (wid >= N) return;
  int r = __builtin_amdgcn_readfirstlane(wid);
  int cp = lane & 31;  // column pair: cols {2cp, 2cp+1}
  int rs = lane >> 5;  // row slot: even/odd edge
  int start = offs[r], cnt = count[r];
  const _Float16* gp = G + 2 * cp;

  float sx = 0.f, sy = 0.f;
  if (rs == 0) {  // self row once
    half2v v = *(const half2v*)(gp + (size_t)r * 64);
    sx += (float)v[0]; sy += (float)v[1];
  }
  for (int j = 0; j < cnt; j += 32) {
    half2v v[16];
    bool a[16];
#pragma unroll
    for (int u = 0; u < 16; u++) {
      int idx = j + 2 * u + rs;
      a[u] = idx < cnt;
      int e = slot[start + min(idx, cnt - 1)];
      v[u] = *(const half2v*)(gp + (size_t)e * 64);
    }
#pragma unroll
    for (int u = 0; u < 16; u++) {
      if (a[u]) { sx += (float)v[u][0]; sy += (float)v[u][1]; }
    }
  }
  // merge even/odd edge halves
  sx += __shfl_xor(sx, 32, 64);
  sy += __shfl_xor(sy, 32, 64);

  if (rs == 0) {
    float d = dinv[r];
    float vx = bias[2 * cp] + d * sx;
    float vy = bias[2 * cp + 1] + d * sy;
    if (do_relu) { vx = fmaxf(vx, 0.f); vy = fmaxf(vy, 0.f); }
    if constexpr (sizeof(TOUT) == 2) {
      half2v o; o[0] = (_Float16)vx; o[1] = (_Float16)vy;
      *(half2v*)((_Float16*)Out + (size_t)r * 64 + 2 * cp) = o;
    } else {
      *(float2*)((float*)Out + (size_t)r * 64 + 2 * cp) = make_float2(vx, vy);
    }
  }
}

// ---- propensity head via MFMA: tprob = lrelu(lrelu(Z@Wp1+bp1)@Wp2+bp2) ----
__launch_bounds__(256)
__global__ void k_tprob_mfma(const float* __restrict__ Z, const float* __restrict__ Wp1,
                             const float* __restrict__ bp1, const float* __restrict__ Wp2,
                             const float* __restrict__ bp2, float* __restrict__ tprob, int N) {
  int lane = threadIdx.x & 63;
  int wv = threadIdx.x >> 6;
  int lo = lane & 15;
  int hi = lane >> 4;

  half8 bfrag[2][4];
#pragma unroll
  for (int ks = 0; ks < 2; ks++)
#pragma unroll
    for (int ct = 0; ct < 4; ct++)
#pragma unroll
      for (int j = 0; j < 8; j++)
        bfrag[ks][ct][j] = (_Float16)Wp1[(ks * 32 + hi * 8 + j) * 64 + ct * 16 + lo];

  int r0 = (blockIdx.x * 4 + wv) * 16;
  if (r0 >= N) return;

  f32x4 acc[4];
#pragma unroll
  for (int ct = 0; ct < 4; ct++)
#pragma unroll
    for (int j = 0; j < 4; j++) acc[ct][j] = 0.0f;

  int ar = min(r0 + lo, N - 1);
#pragma unroll
  for (int ks = 0; ks < 2; ks++) {
    const float4* p = (const float4*)(Z + (size_t)ar * 64 + ks * 32 + hi * 8);
    float4 u = p[0], v = p[1];
    half8 a;
    a[0] = (_Float16)u.x; a[1] = (_Float16)u.y; a[2] = (_Float16)u.z; a[3] = (_Float16)u.w;
    a[4] = (_Float16)v.x; a[5] = (_Float16)v.y; a[6] = (_Float16)v.z; a[7] = (_Float16)v.w;
#pragma unroll
    for (int ct = 0; ct < 4; ct++)
      acc[ct] = __builtin_amdgcn_mfma_f32_16x16x32_f16(a, bfrag[ks][ct], acc[ct], 0, 0, 0);
  }

  float w20[4], w21[4], b1v[4];
#pragma unroll
  for (int ct = 0; ct < 4; ct++) {
    int col = ct * 16 + lo;
    w20[ct] = Wp2[col * 2 + 0];
    w21[ct] = Wp2[col * 2 + 1];
    b1v[ct] = bp1[col];
  }
  float b20 = bp2[0], b21 = bp2[1];

#pragma unroll
  for (int j = 0; j < 4; j++) {
    float t0 = 0.f, t1 = 0.f;
#pragma unroll
    for (int ct = 0; ct < 4; ct++) {
      float h = lrelu(acc[ct][j] + b1v[ct]);
      t0 = fmaf(h, w20[ct], t0);
      t1 = fmaf(h, w21[ct], t1);
    }
#pragma unroll
    for (int m = 1; m <= 8; m <<= 1) {
      t0 += __shfl_xor(t0, m, 64);
      t1 += __shfl_xor(t1, m, 64);
    }
    int rr = r0 + hi * 4 + j;
    if (lo == 0 && rr < N) {
      tprob[(size_t)rr * 2 + 0] = lrelu(t0 + b20);
      tprob[(size_t)rr * 2 + 1] = lrelu(t1 + b21);
    }
  }
}

// ---- outcome heads ----
__global__ void k_heads(const float* __restrict__ Z, const int* __restrict__ treat,
                        const int* __restrict__ ctrl, int T, int C,
                        const float* __restrict__ Wy1, const float* __restrict__ by1,
                        const float* __restrict__ Wy0, const float* __restrict__ by0,
                        float* __restrict__ y1, float* __restrict__ yc0,
                        float* __restrict__ y0, float* __restrict__ yc1) {
  int lane = threadIdx.x & 63;
  int wid = (blockIdx.x * blockDim.x + threadIdx.x) >> 6;
  if (wid >= T + C) return;
  bool treated = wid < T;
  int idx = treated ? wid : wid - T;
  int row = treated ? treat[idx] : ctrl[idx];
  row = __builtin_amdgcn_readfirstlane(row);
  float v = Z[(size_t)row * 64 + lane];
  float s1 = wave_sum64(v * Wy1[lane]);
  float s0 = wave_sum64(v * Wy0[lane]);
  if (lane == 0) {
    float a1 = lrelu(s1 + by1[0]);
    float a0 = lrelu(s0 + by0[0]);
    if (treated) { y1[idx] = a1; yc0[idx] = a0; }
    else         { yc1[idx] = a1; y0[idx] = a0; }
  }
}

extern "C" void kernel_launch(void* const* d_in, const int* in_sizes, int n_in,
                              void* d_out, int out_size, void* d_ws, size_t ws_size,
                              hipStream_t stream) {
  const int IN = 128, H = 64;
  const int N = in_sizes[0] / IN;
  const int E = in_sizes[1] / 2;
  const int T = in_sizes[2];
  const int C = in_sizes[3];
  const int nbuck = (N + 127) >> BSH;         // 782
  const int nblk = (E + CHUNK - 1) / CHUNK;   // 98

  const float* x    = (const float*)d_in[0];
  const int*   ei   = (const int*)d_in[1];
  const int*   src  = ei;
  const int*   dst  = ei + E;
  const int*   trt  = (const int*)d_in[2];
  const int*   ctl  = (const int*)d_in[3];
  const float* W1   = (const float*)d_in[4];
  const float* b1   = (const float*)d_in[5];
  const float* W2   = (const float*)d_in[6];
  const float* b2   = (const float*)d_in[7];
  const float* Wy1  = (const float*)d_in[8];
  const float* by1  = (const float*)d_in[9];
  const float* Wy0  = (const float*)d_in[10];
  const float* by0  = (const float*)d_in[11];
  const float* Wp1  = (const float*)d_in[12];
  const float* bp1  = (const float*)d_in[13];
  const float* Wp2  = (const float*)d_in[14];
  const float* bp2  = (const float*)d_in[15];

  float* out   = (float*)d_out;
  float* y1    = out;                          // [T]
  float* yc0   = out + T;                      // [T]
  float* y0    = out + 2 * T;                  // [C]
  float* yc1   = out + 2 * T + C;              // [C]
  float* tprob = out + 2 * T + 2 * C;          // [N,2]
  float* xZ2   = out + 2 * T + 2 * C + 2 * N;  // [N,64]

  // workspace layout (4-byte units)
  int* cur       = (int*)d_ws;                      // 1024 (zeroed)
  int* offs      = cur + 1024;                      // N
  int* cnt       = offs + N;                        // N
  float* dinv    = (float*)(cnt + N);               // N
  unsigned int* pairs = (unsigned int*)(dinv + N);  // nbuck*CAP (slab; becomes slot)
  _Float16* g16  = (_Float16*)(pairs + (size_t)nbuck * CAP);  // N*64 halves
  _Float16* xZ1  = g16 + (size_t)N * 64;                      // N*64 halves

  hipMemsetAsync(cur, 0, sizeof(int) * 1024, stream);

  k_bin<<<nblk, 256, 0, stream>>>(src, dst, E, nbuck, cur, pairs);
  k_sort<<<nbuck, 256, 0, stream>>>(pairs, cur, offs, cnt, dinv, N);

  const int ngemm = (N + 63) / 64;
  const int nagg = (int)(((size_t)N * 64 + 255) / 256);
  int* slot = (int*)pairs;  // sorted src indices after k_sort

  // layer 1
  k_gemm_mfma<128, float><<<ngemm, 256, 0, stream>>>(x, W1, dinv, g16, N);
  k_agg<_Float16><<<nagg, 256, 0, stream>>>(g16, offs, cnt, slot, dinv, b1, xZ1, N, 1);

  // layer 2
  k_gemm_mfma<64, _Float16><<<ngemm, 256, 0, stream>>>(xZ1, W2, dinv, g16, N);
  k_agg<float><<<nagg, 256, 0, stream>>>(g16, offs, cnt, slot, dinv, b2, xZ2, N, 0);

  // heads
  k_tprob_mfma<<<ngemm, 256, 0, stream>>>(xZ2, Wp1, bp1, Wp2, bp2, tprob, N);
  k_heads<<<((size_t)(T + C) * 64 + 255) / 256, 256, 0, stream>>>(
      xZ2, trt, ctl, T, C, Wy1, by1, Wy0, by0, y1, yc0, y0, yc1);
}

// Round 10
// 190.800 us; speedup vs baseline: 1.5478x; 1.0707x over previous
//
#include <hip/hip_runtime.h>
#include <math.h>

// ---------------------------------------------------------------------------
// CNE: 2-layer GCN (PyG GCNConv norm w/ self loops) + outcome/propensity heads
// N=100000, E=1600000, IN=128, H=64, T=C=20000.
//
// R10: k_bin at 1024 threads/block (16 waves) — R9's 60us was grid starvation
// (98 blocks x 4 waves, occ 3.4%, VALUBusy 1%). Same CHUNK=16384 so the
// per-(block,bucket) scatter runs (~21 entries) keep write coalescing.
// Agg is at its random-line miss-service floor (~2.9TB/s, invariant across
// R4/R6/R8 loop shapes) — left unchanged.
// ---------------------------------------------------------------------------

#define CHUNK 16384  // edges per binning block
#define BSH 7        // 128 dst nodes per bucket
#define CAP 3072     // slab capacity per bucket (mean 2046, max ~2250)

typedef __attribute__((ext_vector_type(8))) _Float16 half8;
typedef __attribute__((ext_vector_type(2))) _Float16 half2v;
typedef __attribute__((ext_vector_type(4))) float f32x4;

__device__ __forceinline__ float lrelu(float x) { return x > 0.0f ? x : 0.01f * x; }

__device__ __forceinline__ float wave_sum64(float v) {
#pragma unroll
  for (int m = 32; m >= 1; m >>= 1) v += __shfl_xor(v, m, 64);
  return v;
}

// ---- fused bin: LDS hist -> global range reservation -> slab scatter ----
__launch_bounds__(1024)
__global__ void k_bin(const int* __restrict__ src, const int* __restrict__ dst,
                      int E, int nbuck, int* __restrict__ cur,
                      unsigned int* __restrict__ pairs) {
  __shared__ int bh[1024];  // per-bucket count, then per-bucket cursor
  __shared__ int bb[1024];  // per-bucket reserved base
  int t = threadIdx.x;
  for (int i = t; i < nbuck; i += 1024) bh[i] = 0;
  __syncthreads();
  int e0 = blockIdx.x * CHUNK;
  int e1 = min(e0 + CHUNK, E);
  for (int e = e0 + t; e < e1; e += 1024) atomicAdd(&bh[dst[e] >> BSH], 1);
  __syncthreads();
  for (int i = t; i < nbuck; i += 1024) {
    int c = bh[i];
    bb[i] = c ? atomicAdd(&cur[i], c) : 0;
  }
  __syncthreads();
  for (int i = t; i < nbuck; i += 1024) bh[i] = 0;  // reuse as intra-block cursor
  __syncthreads();
  for (int e = e0 + t; e < e1; e += 1024) {
    int s = src[e];
    int d = dst[e];
    int b = d >> BSH;
    int p = atomicAdd(&bh[b], 1);
    pairs[(size_t)b * CAP + bb[b] + p] = (unsigned int)s | ((unsigned int)(d & 127) << 20);
  }
}

// ---- in-bucket sort (LDS-staged, in-place slab) -> per-node CSR + dinv ----
__global__ void k_sort(unsigned int* __restrict__ pairs, const int* __restrict__ cur,
                       int* __restrict__ offs, int* __restrict__ cntout,
                       float* __restrict__ dinv, int N) {
  __shared__ unsigned int seg[CAP];
  __shared__ int hist[128];
  __shared__ int loc[128];
  __shared__ int lcur[128];
  int b = blockIdx.x, t = threadIdx.x;
  int c = cur[b];
  size_t base = (size_t)b * CAP;
  for (int i = t; i < c; i += 256) seg[i] = pairs[base + i];
  if (t < 128) hist[t] = 0;
  __syncthreads();  // all global reads of this block's slab segment done
  for (int i = t; i < c; i += 256) atomicAdd(&hist[seg[i] >> 20], 1);
  __syncthreads();
  if (t < 128) loc[t] = hist[t];
  __syncthreads();
  for (int off = 1; off < 128; off <<= 1) {
    int u = (t >= off && t < 128) ? loc[t - off] : 0;
    __syncthreads();
    if (t < 128) loc[t] += u;
    __syncthreads();
  }
  if (t < 128) {
    int ex = loc[t] - hist[t];  // exclusive scan
    lcur[t] = ex;
    int node = (b << BSH) + t;
    if (node < N) {
      offs[node] = (int)base + ex;
      cntout[node] = hist[t];
      dinv[node] = rsqrtf((float)(hist[t] + 1));
    }
  }
  __syncthreads();
  for (int i = t; i < c; i += 256) {
    unsigned int p = seg[i];
    int d = (int)(p >> 20);
    int pos = atomicAdd(&lcur[d], 1);
    pairs[base + pos] = p & 0xFFFFFu;  // sorted src index (consumed as int)
  }
}

// ---- MFMA GEMM: G16 = fp16( dinv * (X @ W) ), X:[N,K] (TIN), W:[K,64] f32 ----
template <int K, typename TIN>
__launch_bounds__(256)
__global__ void k_gemm_mfma(const TIN* __restrict__ X, const float* __restrict__ W,
                            const float* __restrict__ dinv, _Float16* __restrict__ G, int N) {
  constexpr int KST = K / 32;
  int lane = threadIdx.x & 63;
  int wv = threadIdx.x >> 6;
  int lo = lane & 15;   // A row / B,D col (within tile)
  int hi = lane >> 4;   // k-group for A/B; row-group for D

  half8 bfrag[KST][4];
#pragma unroll
  for (int ks = 0; ks < KST; ks++)
#pragma unroll
    for (int ct = 0; ct < 4; ct++)
#pragma unroll
      for (int j = 0; j < 8; j++)
        bfrag[ks][ct][j] = (_Float16)W[(ks * 32 + hi * 8 + j) * 64 + ct * 16 + lo];

  int r0 = (blockIdx.x * 4 + wv) * 16;
  if (r0 >= N) return;

  f32x4 acc[4];
#pragma unroll
  for (int ct = 0; ct < 4; ct++)
#pragma unroll
    for (int j = 0; j < 4; j++) acc[ct][j] = 0.0f;

  int ar = min(r0 + lo, N - 1);
#pragma unroll
  for (int ks = 0; ks < KST; ks++) {
    const TIN* ap = X + (size_t)ar * K + ks * 32 + hi * 8;
    half8 a;
    if constexpr (sizeof(TIN) == 4) {
      const float4* p = (const float4*)ap;
      float4 u = p[0], v = p[1];
      a[0] = (_Float16)u.x; a[1] = (_Float16)u.y; a[2] = (_Float16)u.z; a[3] = (_Float16)u.w;
      a[4] = (_Float16)v.x; a[5] = (_Float16)v.y; a[6] = (_Float16)v.z; a[7] = (_Float16)v.w;
    } else {
      a = *(const half8*)ap;
    }
#pragma unroll
    for (int ct = 0; ct < 4; ct++)
      acc[ct] = __builtin_amdgcn_mfma_f32_16x16x32_f16(a, bfrag[ks][ct], acc[ct], 0, 0, 0);
  }

  float dv[4];
#pragma unroll
  for (int j = 0; j < 4; j++) dv[j] = dinv[min(r0 + hi * 4 + j, N - 1)];
#pragma unroll
  for (int j = 0; j < 4; j++) {
    int rr = r0 + hi * 4 + j;
    if (rr < N) {
#pragma unroll
      for (int ct = 0; ct < 4; ct++)
        G[(size_t)rr * 64 + ct * 16 + lo] = (_Float16)(acc[ct][j] * dv[j]);
    }
  }
}

// ---- aggregation: wave per node, half2/lane, 32-edge predicated window ----
template <typename TOUT>
__launch_bounds__(256)
__global__ void k_agg(const _Float16* __restrict__ G, const int* __restrict__ offs,
                      const int* __restrict__ count, const int* __restrict__ slot,
                      const float* __restrict__ dinv, const float* __restrict__ bias,
                      TOUT* __restrict__ Out, int N, int do_relu) {
  int lane = threadIdx.x & 63;
  int wid = (blockIdx.x * blockDim.x + threadIdx.x) >> 6;
  if (wid >= N) return;
  int r = __builtin_amdgcn_readfirstlane(wid);
  int cp = lane & 31;  // column pair: cols {2cp, 2cp+1}
  int rs = lane >> 5;  // row slot: even/odd edge
  int start = offs[r], cnt = count[r];
  const _Float16* gp = G + 2 * cp;

  float sx = 0.f, sy = 0.f;
  if (rs == 0) {  // self row once
    half2v v = *(const half2v*)(gp + (size_t)r * 64);
    sx += (float)v[0]; sy += (float)v[1];
  }
  for (int j = 0; j < cnt; j += 32) {
    half2v v[16];
    bool a[16];
#pragma unroll
    for (int u = 0; u < 16; u++) {
      int idx = j + 2 * u + rs;
      a[u] = idx < cnt;
      int e = slot[start + min(idx, cnt - 1)];
      v[u] = *(const half2v*)(gp + (size_t)e * 64);
    }
#pragma unroll
    for (int u = 0; u < 16; u++) {
      if (a[u]) { sx += (float)v[u][0]; sy += (float)v[u][1]; }
    }
  }
  // merge even/odd edge halves
  sx += __shfl_xor(sx, 32, 64);
  sy += __shfl_xor(sy, 32, 64);

  if (rs == 0) {
    float d = dinv[r];
    float vx = bias[2 * cp] + d * sx;
    float vy = bias[2 * cp + 1] + d * sy;
    if (do_relu) { vx = fmaxf(vx, 0.f); vy = fmaxf(vy, 0.f); }
    if constexpr (sizeof(TOUT) == 2) {
      half2v o; o[0] = (_Float16)vx; o[1] = (_Float16)vy;
      *(half2v*)((_Float16*)Out + (size_t)r * 64 + 2 * cp) = o;
    } else {
      *(float2*)((float*)Out + (size_t)r * 64 + 2 * cp) = make_float2(vx, vy);
    }
  }
}

// ---- propensity head via MFMA: tprob = lrelu(lrelu(Z@Wp1+bp1)@Wp2+bp2) ----
__launch_bounds__(256)
__global__ void k_tprob_mfma(const float* __restrict__ Z, const float* __restrict__ Wp1,
                             const float* __restrict__ bp1, const float* __restrict__ Wp2,
                             const float* __restrict__ bp2, float* __restrict__ tprob, int N) {
  int lane = threadIdx.x & 63;
  int wv = threadIdx.x >> 6;
  int lo = lane & 15;
  int hi = lane >> 4;

  half8 bfrag[2][4];
#pragma unroll
  for (int ks = 0; ks < 2; ks++)
#pragma unroll
    for (int ct = 0; ct < 4; ct++)
#pragma unroll
      for (int j = 0; j < 8; j++)
        bfrag[ks][ct][j] = (_Float16)Wp1[(ks * 32 + hi * 8 + j) * 64 + ct * 16 + lo];

  int r0 = (blockIdx.x * 4 + wv) * 16;
  if (r0 >= N) return;

  f32x4 acc[4];
#pragma unroll
  for (int ct = 0; ct < 4; ct++)
#pragma unroll
    for (int j = 0; j < 4; j++) acc[ct][j] = 0.0f;

  int ar = min(r0 + lo, N - 1);
#pragma unroll
  for (int ks = 0; ks < 2; ks++) {
    const float4* p = (const float4*)(Z + (size_t)ar * 64 + ks * 32 + hi * 8);
    float4 u = p[0], v = p[1];
    half8 a;
    a[0] = (_Float16)u.x; a[1] = (_Float16)u.y; a[2] = (_Float16)u.z; a[3] = (_Float16)u.w;
    a[4] = (_Float16)v.x; a[5] = (_Float16)v.y; a[6] = (_Float16)v.z; a[7] = (_Float16)v.w;
#pragma unroll
    for (int ct = 0; ct < 4; ct++)
      acc[ct] = __builtin_amdgcn_mfma_f32_16x16x32_f16(a, bfrag[ks][ct], acc[ct], 0, 0, 0);
  }

  float w20[4], w21[4], b1v[4];
#pragma unroll
  for (int ct = 0; ct < 4; ct++) {
    int col = ct * 16 + lo;
    w20[ct] = Wp2[col * 2 + 0];
    w21[ct] = Wp2[col * 2 + 1];
    b1v[ct] = bp1[col];
  }
  float b20 = bp2[0], b21 = bp2[1];

#pragma unroll
  for (int j = 0; j < 4; j++) {
    float t0 = 0.f, t1 = 0.f;
#pragma unroll
    for (int ct = 0; ct < 4; ct++) {
      float h = lrelu(acc[ct][j] + b1v[ct]);
      t0 = fmaf(h, w20[ct], t0);
      t1 = fmaf(h, w21[ct], t1);
    }
#pragma unroll
    for (int m = 1; m <= 8; m <<= 1) {
      t0 += __shfl_xor(t0, m, 64);
      t1 += __shfl_xor(t1, m, 64);
    }
    int rr = r0 + hi * 4 + j;
    if (lo == 0 && rr < N) {
      tprob[(size_t)rr * 2 + 0] = lrelu(t0 + b20);
      tprob[(size_t)rr * 2 + 1] = lrelu(t1 + b21);
    }
  }
}

// ---- outcome heads ----
__global__ void k_heads(const float* __restrict__ Z, const int* __restrict__ treat,
                        const int* __restrict__ ctrl, int T, int C,
                        const float* __restrict__ Wy1, const float* __restrict__ by1,
                        const float* __restrict__ Wy0, const float* __restrict__ by0,
                        float* __restrict__ y1, float* __restrict__ yc0,
                        float* __restrict__ y0, float* __restrict__ yc1) {
  int lane = threadIdx.x & 63;
  int wid = (blockIdx.x * blockDim.x + threadIdx.x) >> 6;
  if (wid >= T + C) return;
  bool treated = wid < T;
  int idx = treated ? wid : wid - T;
  int row = treated ? treat[idx] : ctrl[idx];
  row = __builtin_amdgcn_readfirstlane(row);
  float v = Z[(size_t)row * 64 + lane];
  float s1 = wave_sum64(v * Wy1[lane]);
  float s0 = wave_sum64(v * Wy0[lane]);
  if (lane == 0) {
    float a1 = lrelu(s1 + by1[0]);
    float a0 = lrelu(s0 + by0[0]);
    if (treated) { y1[idx] = a1; yc0[idx] = a0; }
    else         { yc1[idx] = a1; y0[idx] = a0; }
  }
}

extern "C" void kernel_launch(void* const* d_in, const int* in_sizes, int n_in,
                              void* d_out, int out_size, void* d_ws, size_t ws_size,
                              hipStream_t stream) {
  const int IN = 128, H = 64;
  const int N = in_sizes[0] / IN;
  const int E = in_sizes[1] / 2;
  const int T = in_sizes[2];
  const int C = in_sizes[3];
  const int nbuck = (N + 127) >> BSH;         // 782
  const int nblk = (E + CHUNK - 1) / CHUNK;   // 98

  const float* x    = (const float*)d_in[0];
  const int*   ei   = (const int*)d_in[1];
  const int*   src  = ei;
  const int*   dst  = ei + E;
  const int*   trt  = (const int*)d_in[2];
  const int*   ctl  = (const int*)d_in[3];
  const float* W1   = (const float*)d_in[4];
  const float* b1   = (const float*)d_in[5];
  const float* W2   = (const float*)d_in[6];
  const float* b2   = (const float*)d_in[7];
  const float* Wy1  = (const float*)d_in[8];
  const float* by1  = (const float*)d_in[9];
  const float* Wy0  = (const float*)d_in[10];
  const float* by0  = (const float*)d_in[11];
  const float* Wp1  = (const float*)d_in[12];
  const float* bp1  = (const float*)d_in[13];
  const float* Wp2  = (const float*)d_in[14];
  const float* bp2  = (const float*)d_in[15];

  float* out   = (float*)d_out;
  float* y1    = out;                          // [T]
  float* yc0   = out + T;                      // [T]
  float* y0    = out + 2 * T;                  // [C]
  float* yc1   = out + 2 * T + C;              // [C]
  float* tprob = out + 2 * T + 2 * C;          // [N,2]
  float* xZ2   = out + 2 * T + 2 * C + 2 * N;  // [N,64]

  // workspace layout (4-byte units)
  int* cur       = (int*)d_ws;                      // 1024 (zeroed)
  int* offs      = cur + 1024;                      // N
  int* cnt       = offs + N;                        // N
  float* dinv    = (float*)(cnt + N);               // N
  unsigned int* pairs = (unsigned int*)(dinv + N);  // nbuck*CAP (slab; becomes slot)
  _Float16* g16  = (_Float16*)(pairs + (size_t)nbuck * CAP);  // N*64 halves
  _Float16* xZ1  = g16 + (size_t)N * 64;                      // N*64 halves

  hipMemsetAsync(cur, 0, sizeof(int) * 1024, stream);

  k_bin<<<nblk, 1024, 0, stream>>>(src, dst, E, nbuck, cur, pairs);
  k_sort<<<nbuck, 256, 0, stream>>>(pairs, cur, offs, cnt, dinv, N);

  const int ngemm = (N + 63) / 64;
  const int nagg = (int)(((size_t)N * 64 + 255) / 256);
  int* slot = (int*)pairs;  // sorted src indices after k_sort

  // layer 1
  k_gemm_mfma<128, float><<<ngemm, 256, 0, stream>>>(x, W1, dinv, g16, N);
  k_agg<_Float16><<<nagg, 256, 0, stream>>>(g16, offs, cnt, slot, dinv, b1, xZ1, N, 1);

  // layer 2
  k_gemm_mfma<64, _Float16><<<ngemm, 256, 0, stream>>>(xZ1, W2, dinv, g16, N);
  k_agg<float><<<nagg, 256, 0, stream>>>(g16, offs, cnt, slot, dinv, b2, xZ2, N, 0);

  // heads
  k_tprob_mfma<<<ngemm, 256, 0, stream>>>(xZ2, Wp1, bp1, Wp2, bp2, tprob, N);
  k_heads<<<((size_t)(T + C) * 64 + 255) / 256, 256, 0, stream>>>(
      xZ2, trt, ctl, T, C, Wy1, by1, Wy0, by0, y1, yc0, y0, yc1);
}

// Round 11
// 174.510 us; speedup vs baseline: 1.6923x; 1.0933x over previous
//
#include <hip/hip_runtime.h>
#include <math.h>

// ---------------------------------------------------------------------------
// CNE: 2-layer GCN (PyG GCNConv norm w/ self loops) + outcome/propensity heads
// N=100000, E=1600000, IN=128, H=64, T=C=20000.
//
// R11:
//  - agg: predication-free inner loop. k_sort pads each node's slot list to
//    a multiple of 32 with sentinel index N -> G[N] is a zero row (written by
//    gemm block 0). Pure load+add window.
//  - k_bin: CHUNK 8192 (196 blocks x 1024 thr) for 2x latency concurrency.
//  - tprob + heads merged into one launch (block-level branch).
// ---------------------------------------------------------------------------

#define CHUNK 8192   // edges per binning block
#define BSH 7        // 128 dst nodes per bucket
#define CAP 4608     // slab capacity per bucket (padded sum <= ~4300)

typedef __attribute__((ext_vector_type(8))) _Float16 half8;
typedef __attribute__((ext_vector_type(2))) _Float16 half2v;
typedef __attribute__((ext_vector_type(4))) float f32x4;

__device__ __forceinline__ float lrelu(float x) { return x > 0.0f ? x : 0.01f * x; }

__device__ __forceinline__ float wave_sum64(float v) {
#pragma unroll
  for (int m = 32; m >= 1; m >>= 1) v += __shfl_xor(v, m, 64);
  return v;
}

// ---- fused bin: LDS hist -> global range reservation -> slab scatter ----
__launch_bounds__(1024)
__global__ void k_bin(const int* __restrict__ src, const int* __restrict__ dst,
                      int E, int nbuck, int* __restrict__ cur,
                      unsigned int* __restrict__ pairs) {
  __shared__ int bh[1024];  // per-bucket count, then per-bucket cursor
  __shared__ int bb[1024];  // per-bucket reserved base
  int t = threadIdx.x;
  for (int i = t; i < nbuck; i += 1024) bh[i] = 0;
  __syncthreads();
  int e0 = blockIdx.x * CHUNK;
  int e1 = min(e0 + CHUNK, E);
  for (int e = e0 + t; e < e1; e += 1024) atomicAdd(&bh[dst[e] >> BSH], 1);
  __syncthreads();
  for (int i = t; i < nbuck; i += 1024) {
    int c = bh[i];
    bb[i] = c ? atomicAdd(&cur[i], c) : 0;
  }
  __syncthreads();
  for (int i = t; i < nbuck; i += 1024) bh[i] = 0;  // reuse as intra-block cursor
  __syncthreads();
  for (int e = e0 + t; e < e1; e += 1024) {
    int s = src[e];
    int d = dst[e];
    int b = d >> BSH;
    int p = atomicAdd(&bh[b], 1);
    pairs[(size_t)b * CAP + bb[b] + p] = (unsigned int)s | ((unsigned int)(d & 127) << 20);
  }
}

// ---- in-bucket sort (LDS-staged, in-place slab) -> padded per-node CSR ----
// Node lists padded to multiple of 32 with sentinel index N (zero G row).
__global__ void k_sort(unsigned int* __restrict__ pairs, const int* __restrict__ cur,
                       int* __restrict__ offs, int* __restrict__ cntout,
                       float* __restrict__ dinv, int N) {
  __shared__ unsigned int seg[CAP];
  __shared__ int hist[128];
  __shared__ int loc[128];
  __shared__ int lcur[128];
  __shared__ int pbase[128];
  int b = blockIdx.x, t = threadIdx.x;
  int c = cur[b];
  size_t base = (size_t)b * CAP;
  for (int i = t; i < c; i += 256) seg[i] = pairs[base + i];
  if (t < 128) hist[t] = 0;
  __syncthreads();  // all global reads of this block's slab segment done
  for (int i = t; i < c; i += 256) atomicAdd(&hist[seg[i] >> 20], 1);
  __syncthreads();
  if (t < 128) loc[t] = (hist[t] + 31) & ~31;  // padded length
  __syncthreads();
  for (int off = 1; off < 128; off <<= 1) {
    int u = (t >= off && t < 128) ? loc[t - off] : 0;
    __syncthreads();
    if (t < 128) loc[t] += u;
    __syncthreads();
  }
  if (t < 128) {
    int r32 = (hist[t] + 31) & ~31;
    int pex = loc[t] - r32;  // padded exclusive scan
    lcur[t] = pex;
    pbase[t] = pex;
    int node = (b << BSH) + t;
    if (node < N) {
      offs[node] = (int)base + pex;
      cntout[node] = r32;                         // padded count (agg loop bound)
      dinv[node] = rsqrtf((float)(hist[t] + 1));  // real degree for norm
    }
  }
  __syncthreads();
  for (int i = t; i < c; i += 256) {
    unsigned int p = seg[i];
    int d = (int)(p >> 20);
    int pos = atomicAdd(&lcur[d], 1);
    pairs[base + pos] = p & 0xFFFFFu;  // sorted src index
  }
  __syncthreads();
  if (t < 128) {
    int r32 = (hist[t] + 31) & ~31;
    for (int p = hist[t]; p < r32; p++) pairs[base + pbase[t] + p] = (unsigned int)N;
  }
}

// ---- MFMA GEMM: G16 = fp16( dinv * (X @ W) ); also zeroes G row N ----
template <int K, typename TIN>
__launch_bounds__(256)
__global__ void k_gemm_mfma(const TIN* __restrict__ X, const float* __restrict__ W,
                            const float* __restrict__ dinv, _Float16* __restrict__ G, int N) {
  constexpr int KST = K / 32;
  int lane = threadIdx.x & 63;
  int wv = threadIdx.x >> 6;
  int lo = lane & 15;   // A row / B,D col (within tile)
  int hi = lane >> 4;   // k-group for A/B; row-group for D

  if (blockIdx.x == 0 && threadIdx.x < 64) G[(size_t)N * 64 + threadIdx.x] = (_Float16)0.0f;

  half8 bfrag[KST][4];
#pragma unroll
  for (int ks = 0; ks < KST; ks++)
#pragma unroll
    for (int ct = 0; ct < 4; ct++)
#pragma unroll
      for (int j = 0; j < 8; j++)
        bfrag[ks][ct][j] = (_Float16)W[(ks * 32 + hi * 8 + j) * 64 + ct * 16 + lo];

  int r0 = (blockIdx.x * 4 + wv) * 16;
  if (r0 >= N) return;

  f32x4 acc[4];
#pragma unroll
  for (int ct = 0; ct < 4; ct++)
#pragma unroll
    for (int j = 0; j < 4; j++) acc[ct][j] = 0.0f;

  int ar = min(r0 + lo, N - 1);
#pragma unroll
  for (int ks = 0; ks < KST; ks++) {
    const TIN* ap = X + (size_t)ar * K + ks * 32 + hi * 8;
    half8 a;
    if constexpr (sizeof(TIN) == 4) {
      const float4* p = (const float4*)ap;
      float4 u = p[0], v = p[1];
      a[0] = (_Float16)u.x; a[1] = (_Float16)u.y; a[2] = (_Float16)u.z; a[3] = (_Float16)u.w;
      a[4] = (_Float16)v.x; a[5] = (_Float16)v.y; a[6] = (_Float16)v.z; a[7] = (_Float16)v.w;
    } else {
      a = *(const half8*)ap;
    }
#pragma unroll
    for (int ct = 0; ct < 4; ct++)
      acc[ct] = __builtin_amdgcn_mfma_f32_16x16x32_f16(a, bfrag[ks][ct], acc[ct], 0, 0, 0);
  }

  float dv[4];
#pragma unroll
  for (int j = 0; j < 4; j++) dv[j] = dinv[min(r0 + hi * 4 + j, N - 1)];
#pragma unroll
  for (int j = 0; j < 4; j++) {
    int rr = r0 + hi * 4 + j;
    if (rr < N) {
#pragma unroll
      for (int ct = 0; ct < 4; ct++)
        G[(size_t)rr * 64 + ct * 16 + lo] = (_Float16)(acc[ct][j] * dv[j]);
    }
  }
}

// ---- aggregation: wave per node, half2/lane, predication-free 32-window ----
template <typename TOUT>
__launch_bounds__(256)
__global__ void k_agg(const _Float16* __restrict__ G, const int* __restrict__ offs,
                      const int* __restrict__ count, const int* __restrict__ slot,
                      const float* __restrict__ dinv, const float* __restrict__ bias,
                      TOUT* __restrict__ Out, int N, int do_relu) {
  int lane = threadIdx.x & 63;
  int wid = (blockIdx.x * blockDim.x + threadIdx.x) >> 6;
  if (wid >= N) return;
  int r = __builtin_amdgcn_readfirstlane(wid);
  int cp = lane & 31;  // column pair: cols {2cp, 2cp+1}
  int rs = lane >> 5;  // row slot: even/odd edge
  int start = offs[r], cnt = count[r];  // cnt is multiple of 32 (padded)
  const _Float16* gp = G + 2 * cp;

  float sx = 0.f, sy = 0.f;
  if (rs == 0) {  // self row once
    half2v v = *(const half2v*)(gp + (size_t)r * 64);
    sx += (float)v[0]; sy += (float)v[1];
  }
  for (int j = 0; j < cnt; j += 32) {
    half2v v[16];
#pragma unroll
    for (int u = 0; u < 16; u++) {
      int e = slot[start + j + 2 * u + rs];
      v[u] = *(const half2v*)(gp + (size_t)e * 64);
    }
#pragma unroll
    for (int u = 0; u < 16; u++) { sx += (float)v[u][0]; sy += (float)v[u][1]; }
  }
  // merge even/odd edge halves
  sx += __shfl_xor(sx, 32, 64);
  sy += __shfl_xor(sy, 32, 64);

  if (rs == 0) {
    float d = dinv[r];
    float vx = bias[2 * cp] + d * sx;
    float vy = bias[2 * cp + 1] + d * sy;
    if (do_relu) { vx = fmaxf(vx, 0.f); vy = fmaxf(vy, 0.f); }
    if constexpr (sizeof(TOUT) == 2) {
      half2v o; o[0] = (_Float16)vx; o[1] = (_Float16)vy;
      *(half2v*)((_Float16*)Out + (size_t)r * 64 + 2 * cp) = o;
    } else {
      *(float2*)((float*)Out + (size_t)r * 64 + 2 * cp) = make_float2(vx, vy);
    }
  }
}

// ---- merged finish: blocks [0,ngemm) = propensity head (MFMA),
//      blocks [ngemm, ...) = outcome heads ----
__launch_bounds__(256)
__global__ void k_finish(const float* __restrict__ Z,
                         const float* __restrict__ Wp1, const float* __restrict__ bp1,
                         const float* __restrict__ Wp2, const float* __restrict__ bp2,
                         float* __restrict__ tprob,
                         const int* __restrict__ treat, const int* __restrict__ ctrl,
                         int T, int C,
                         const float* __restrict__ Wy1, const float* __restrict__ by1,
                         const float* __restrict__ Wy0, const float* __restrict__ by0,
                         float* __restrict__ y1, float* __restrict__ yc0,
                         float* __restrict__ y0, float* __restrict__ yc1,
                         int N, int ngemm) {
  int lane = threadIdx.x & 63;
  if ((int)blockIdx.x < ngemm) {
    int wv = threadIdx.x >> 6;
    int lo = lane & 15;
    int hi = lane >> 4;

    half8 bfrag[2][4];
#pragma unroll
    for (int ks = 0; ks < 2; ks++)
#pragma unroll
      for (int ct = 0; ct < 4; ct++)
#pragma unroll
        for (int j = 0; j < 8; j++)
          bfrag[ks][ct][j] = (_Float16)Wp1[(ks * 32 + hi * 8 + j) * 64 + ct * 16 + lo];

    int r0 = (blockIdx.x * 4 + wv) * 16;
    if (r0 >= N) return;

    f32x4 acc[4];
#pragma unroll
    for (int ct = 0; ct < 4; ct++)
#pragma unroll
      for (int j = 0; j < 4; j++) acc[ct][j] = 0.0f;

    int ar = min(r0 + lo, N - 1);
#pragma unroll
    for (int ks = 0; ks < 2; ks++) {
      const float4* p = (const float4*)(Z + (size_t)ar * 64 + ks * 32 + hi * 8);
      float4 u = p[0], v = p[1];
      half8 a;
      a[0] = (_Float16)u.x; a[1] = (_Float16)u.y; a[2] = (_Float16)u.z; a[3] = (_Float16)u.w;
      a[4] = (_Float16)v.x; a[5] = (_Float16)v.y; a[6] = (_Float16)v.z; a[7] = (_Float16)v.w;
#pragma unroll
      for (int ct = 0; ct < 4; ct++)
        acc[ct] = __builtin_amdgcn_mfma_f32_16x16x32_f16(a, bfrag[ks][ct], acc[ct], 0, 0, 0);
    }

    float w20[4], w21[4], b1v[4];
#pragma unroll
    for (int ct = 0; ct < 4; ct++) {
      int col = ct * 16 + lo;
      w20[ct] = Wp2[col * 2 + 0];
      w21[ct] = Wp2[col * 2 + 1];
      b1v[ct] = bp1[col];
    }
    float b20 = bp2[0], b21 = bp2[1];

#pragma unroll
    for (int j = 0; j < 4; j++) {
      float t0 = 0.f, t1 = 0.f;
#pragma unroll
      for (int ct = 0; ct < 4; ct++) {
        float h = lrelu(acc[ct][j] + b1v[ct]);
        t0 = fmaf(h, w20[ct], t0);
        t1 = fmaf(h, w21[ct], t1);
      }
#pragma unroll
      for (int m = 1; m <= 8; m <<= 1) {
        t0 += __shfl_xor(t0, m, 64);
        t1 += __shfl_xor(t1, m, 64);
      }
      int rr = r0 + hi * 4 + j;
      if (lo == 0 && rr < N) {
        tprob[(size_t)rr * 2 + 0] = lrelu(t0 + b20);
        tprob[(size_t)rr * 2 + 1] = lrelu(t1 + b21);
      }
    }
  } else {
    int wid = (((int)blockIdx.x - ngemm) * (int)blockDim.x + (int)threadIdx.x) >> 6;
    if (wid >= T + C) return;
    bool treated = wid < T;
    int idx = treated ? wid : wid - T;
    int row = treated ? treat[idx] : ctrl[idx];
    row = __builtin_amdgcn_readfirstlane(row);
    float v = Z[(size_t)row * 64 + lane];
    float s1 = wave_sum64(v * Wy1[lane]);
    float s0 = wave_sum64(v * Wy0[lane]);
    if (lane == 0) {
      float a1 = lrelu(s1 + by1[0]);
      float a0 = lrelu(s0 + by0[0]);
      if (treated) { y1[idx] = a1; yc0[idx] = a0; }
      else         { yc1[idx] = a1; y0[idx] = a0; }
    }
  }
}

extern "C" void kernel_launch(void* const* d_in, const int* in_sizes, int n_in,
                              void* d_out, int out_size, void* d_ws, size_t ws_size,
                              hipStream_t stream) {
  const int IN = 128, H = 64;
  const int N = in_sizes[0] / IN;
  const int E = in_sizes[1] / 2;
  const int T = in_sizes[2];
  const int C = in_sizes[3];
  const int nbuck = (N + 127) >> BSH;         // 782
  const int nblk = (E + CHUNK - 1) / CHUNK;   // 196

  const float* x    = (const float*)d_in[0];
  const int*   ei   = (const int*)d_in[1];
  const int*   src  = ei;
  const int*   dst  = ei + E;
  const int*   trt  = (const int*)d_in[2];
  const int*   ctl  = (const int*)d_in[3];
  const float* W1   = (const float*)d_in[4];
  const float* b1   = (const float*)d_in[5];
  const float* W2   = (const float*)d_in[6];
  const float* b2   = (const float*)d_in[7];
  const float* Wy1  = (const float*)d_in[8];
  const float* by1  = (const float*)d_in[9];
  const float* Wy0  = (const float*)d_in[10];
  const float* by0  = (const float*)d_in[11];
  const float* Wp1  = (const float*)d_in[12];
  const float* bp1  = (const float*)d_in[13];
  const float* Wp2  = (const float*)d_in[14];
  const float* bp2  = (const float*)d_in[15];

  float* out   = (float*)d_out;
  float* y1    = out;                          // [T]
  float* yc0   = out + T;                      // [T]
  float* y0    = out + 2 * T;                  // [C]
  float* yc1   = out + 2 * T + C;              // [C]
  float* tprob = out + 2 * T + 2 * C;          // [N,2]
  float* xZ2   = out + 2 * T + 2 * C + 2 * N;  // [N,64]

  // workspace layout (4-byte units)
  int* cur       = (int*)d_ws;                      // 1024 (zeroed)
  int* offs      = cur + 1024;                      // N
  int* cnt       = offs + N;                        // N
  float* dinv    = (float*)(cnt + N);               // N
  unsigned int* pairs = (unsigned int*)(dinv + N);  // nbuck*CAP (slab; becomes slot)
  _Float16* g16  = (_Float16*)(pairs + (size_t)nbuck * CAP);  // (N+1)*64 halves
  _Float16* xZ1  = g16 + (size_t)(N + 1) * 64;                // N*64 halves

  hipMemsetAsync(cur, 0, sizeof(int) * 1024, stream);

  k_bin<<<nblk, 1024, 0, stream>>>(src, dst, E, nbuck, cur, pairs);
  k_sort<<<nbuck, 256, 0, stream>>>(pairs, cur, offs, cnt, dinv, N);

  const int ngemm = (N + 63) / 64;
  const int nagg = (int)(((size_t)N * 64 + 255) / 256);
  const int nheads = (int)(((size_t)(T + C) * 64 + 255) / 256);
  int* slot = (int*)pairs;  // sorted+padded src indices after k_sort

  // layer 1
  k_gemm_mfma<128, float><<<ngemm, 256, 0, stream>>>(x, W1, dinv, g16, N);
  k_agg<_Float16><<<nagg, 256, 0, stream>>>(g16, offs, cnt, slot, dinv, b1, xZ1, N, 1);

  // layer 2
  k_gemm_mfma<64, _Float16><<<ngemm, 256, 0, stream>>>(xZ1, W2, dinv, g16, N);
  k_agg<float><<<nagg, 256, 0, stream>>>(g16, offs, cnt, slot, dinv, b2, xZ2, N, 0);

  // heads (merged tprob + outcome)
  k_finish<<<ngemm + nheads, 256, 0, stream>>>(
      xZ2, Wp1, bp1, Wp2, bp2, tprob, trt, ctl, T, C,
      Wy1, by1, Wy0, by0, y1, yc0, y0, yc1, N, ngemm);
}

// Round 12
// 173.760 us; speedup vs baseline: 1.6996x; 1.0043x over previous
//
#include <hip/hip_runtime.h>
#include <math.h>

// ---------------------------------------------------------------------------
// CNE: 2-layer GCN (PyG GCNConv norm w/ self loops) + outcome/propensity heads
// N=100000, E=1600000, IN=128, H=64, T=C=20000.
//
// R12: replace hipMemsetAsync(cur, 4KB) with k_zero kernel — the runtime's
// fillBufferAligned node cost 40us/replay in the captured graph (WRITE=4KB,
// occ 8.6%, VALUBusy 4% in R11 profile). Everything else identical to R11.
// ---------------------------------------------------------------------------

#define CHUNK 8192   // edges per binning block
#define BSH 7        // 128 dst nodes per bucket
#define CAP 4608     // slab capacity per bucket (padded sum <= ~4300)

typedef __attribute__((ext_vector_type(8))) _Float16 half8;
typedef __attribute__((ext_vector_type(2))) _Float16 half2v;
typedef __attribute__((ext_vector_type(4))) float f32x4;

__device__ __forceinline__ float lrelu(float x) { return x > 0.0f ? x : 0.01f * x; }

__device__ __forceinline__ float wave_sum64(float v) {
#pragma unroll
  for (int m = 32; m >= 1; m >>= 1) v += __shfl_xor(v, m, 64);
  return v;
}

// ---- zero the 1024-word bucket cursor array ----
__global__ void k_zero(int* __restrict__ cur) { cur[threadIdx.x] = 0; }

// ---- fused bin: LDS hist -> global range reservation -> slab scatter ----
__launch_bounds__(1024)
__global__ void k_bin(const int* __restrict__ src, const int* __restrict__ dst,
                      int E, int nbuck, int* __restrict__ cur,
                      unsigned int* __restrict__ pairs) {
  __shared__ int bh[1024];  // per-bucket count, then per-bucket cursor
  __shared__ int bb[1024];  // per-bucket reserved base
  int t = threadIdx.x;
  for (int i = t; i < nbuck; i += 1024) bh[i] = 0;
  __syncthreads();
  int e0 = blockIdx.x * CHUNK;
  int e1 = min(e0 + CHUNK, E);
  for (int e = e0 + t; e < e1; e += 1024) atomicAdd(&bh[dst[e] >> BSH], 1);
  __syncthreads();
  for (int i = t; i < nbuck; i += 1024) {
    int c = bh[i];
    bb[i] = c ? atomicAdd(&cur[i], c) : 0;
  }
  __syncthreads();
  for (int i = t; i < nbuck; i += 1024) bh[i] = 0;  // reuse as intra-block cursor
  __syncthreads();
  for (int e = e0 + t; e < e1; e += 1024) {
    int s = src[e];
    int d = dst[e];
    int b = d >> BSH;
    int p = atomicAdd(&bh[b], 1);
    pairs[(size_t)b * CAP + bb[b] + p] = (unsigned int)s | ((unsigned int)(d & 127) << 20);
  }
}

// ---- in-bucket sort (LDS-staged, in-place slab) -> padded per-node CSR ----
// Node lists padded to multiple of 32 with sentinel index N (zero G row).
__global__ void k_sort(unsigned int* __restrict__ pairs, const int* __restrict__ cur,
                       int* __restrict__ offs, int* __restrict__ cntout,
                       float* __restrict__ dinv, int N) {
  __shared__ unsigned int seg[CAP];
  __shared__ int hist[128];
  __shared__ int loc[128];
  __shared__ int lcur[128];
  __shared__ int pbase[128];
  int b = blockIdx.x, t = threadIdx.x;
  int c = cur[b];
  size_t base = (size_t)b * CAP;
  for (int i = t; i < c; i += 256) seg[i] = pairs[base + i];
  if (t < 128) hist[t] = 0;
  __syncthreads();  // all global reads of this block's slab segment done
  for (int i = t; i < c; i += 256) atomicAdd(&hist[seg[i] >> 20], 1);
  __syncthreads();
  if (t < 128) loc[t] = (hist[t] + 31) & ~31;  // padded length
  __syncthreads();
  for (int off = 1; off < 128; off <<= 1) {
    int u = (t >= off && t < 128) ? loc[t - off] : 0;
    __syncthreads();
    if (t < 128) loc[t] += u;
    __syncthreads();
  }
  if (t < 128) {
    int r32 = (hist[t] + 31) & ~31;
    int pex = loc[t] - r32;  // padded exclusive scan
    lcur[t] = pex;
    pbase[t] = pex;
    int node = (b << BSH) + t;
    if (node < N) {
      offs[node] = (int)base + pex;
      cntout[node] = r32;                         // padded count (agg loop bound)
      dinv[node] = rsqrtf((float)(hist[t] + 1));  // real degree for norm
    }
  }
  __syncthreads();
  for (int i = t; i < c; i += 256) {
    unsigned int p = seg[i];
    int d = (int)(p >> 20);
    int pos = atomicAdd(&lcur[d], 1);
    pairs[base + pos] = p & 0xFFFFFu;  // sorted src index
  }
  __syncthreads();
  if (t < 128) {
    int r32 = (hist[t] + 31) & ~31;
    for (int p = hist[t]; p < r32; p++) pairs[base + pbase[t] + p] = (unsigned int)N;
  }
}

// ---- MFMA GEMM: G16 = fp16( dinv * (X @ W) ); also zeroes G row N ----
template <int K, typename TIN>
__launch_bounds__(256)
__global__ void k_gemm_mfma(const TIN* __restrict__ X, const float* __restrict__ W,
                            const float* __restrict__ dinv, _Float16* __restrict__ G, int N) {
  constexpr int KST = K / 32;
  int lane = threadIdx.x & 63;
  int wv = threadIdx.x >> 6;
  int lo = lane & 15;   // A row / B,D col (within tile)
  int hi = lane >> 4;   // k-group for A/B; row-group for D

  if (blockIdx.x == 0 && threadIdx.x < 64) G[(size_t)N * 64 + threadIdx.x] = (_Float16)0.0f;

  half8 bfrag[KST][4];
#pragma unroll
  for (int ks = 0; ks < KST; ks++)
#pragma unroll
    for (int ct = 0; ct < 4; ct++)
#pragma unroll
      for (int j = 0; j < 8; j++)
        bfrag[ks][ct][j] = (_Float16)W[(ks * 32 + hi * 8 + j) * 64 + ct * 16 + lo];

  int r0 = (blockIdx.x * 4 + wv) * 16;
  if (r0 >= N) return;

  f32x4 acc[4];
#pragma unroll
  for (int ct = 0; ct < 4; ct++)
#pragma unroll
    for (int j = 0; j < 4; j++) acc[ct][j] = 0.0f;

  int ar = min(r0 + lo, N - 1);
#pragma unroll
  for (int ks = 0; ks < KST; ks++) {
    const TIN* ap = X + (size_t)ar * K + ks * 32 + hi * 8;
    half8 a;
    if constexpr (sizeof(TIN) == 4) {
      const float4* p = (const float4*)ap;
      float4 u = p[0], v = p[1];
      a[0] = (_Float16)u.x; a[1] = (_Float16)u.y; a[2] = (_Float16)u.z; a[3] = (_Float16)u.w;
      a[4] = (_Float16)v.x; a[5] = (_Float16)v.y; a[6] = (_Float16)v.z; a[7] = (_Float16)v.w;
    } else {
      a = *(const half8*)ap;
    }
#pragma unroll
    for (int ct = 0; ct < 4; ct++)
      acc[ct] = __builtin_amdgcn_mfma_f32_16x16x32_f16(a, bfrag[ks][ct], acc[ct], 0, 0, 0);
  }

  float dv[4];
#pragma unroll
  for (int j = 0; j < 4; j++) dv[j] = dinv[min(r0 + hi * 4 + j, N - 1)];
#pragma unroll
  for (int j = 0; j < 4; j++) {
    int rr = r0 + hi * 4 + j;
    if (rr < N) {
#pragma unroll
      for (int ct = 0; ct < 4; ct++)
        G[(size_t)rr * 64 + ct * 16 + lo] = (_Float16)(acc[ct][j] * dv[j]);
    }
  }
}

// ---- aggregation: wave per node, half2/lane, predication-free 32-window ----
template <typename TOUT>
__launch_bounds__(256)
__global__ void k_agg(const _Float16* __restrict__ G, const int* __restrict__ offs,
                      const int* __restrict__ count, const int* __restrict__ slot,
                      const float* __restrict__ dinv, const float* __restrict__ bias,
                      TOUT* __restrict__ Out, int N, int do_relu) {
  int lane = threadIdx.x & 63;
  int wid = (blockIdx.x * blockDim.x + threadIdx.x) >> 6;
  if (wid >= N) return;
  int r = __builtin_amdgcn_readfirstlane(wid);
  int cp = lane & 31;  // column pair: cols {2cp, 2cp+1}
  int rs = lane >> 5;  // row slot: even/odd edge
  int start = offs[r], cnt = count[r];  // cnt is multiple of 32 (padded)
  const _Float16* gp = G + 2 * cp;

  float sx = 0.f, sy = 0.f;
  if (rs == 0) {  // self row once
    half2v v = *(const half2v*)(gp + (size_t)r * 64);
    sx += (float)v[0]; sy += (float)v[1];
  }
  for (int j = 0; j < cnt; j += 32) {
    half2v v[16];
#pragma unroll
    for (int u = 0; u < 16; u++) {
      int e = slot[start + j + 2 * u + rs];
      v[u] = *(const half2v*)(gp + (size_t)e * 64);
    }
#pragma unroll
    for (int u = 0; u < 16; u++) { sx += (float)v[u][0]; sy += (float)v[u][1]; }
  }
  // merge even/odd edge halves
  sx += __shfl_xor(sx, 32, 64);
  sy += __shfl_xor(sy, 32, 64);

  if (rs == 0) {
    float d = dinv[r];
    float vx = bias[2 * cp] + d * sx;
    float vy = bias[2 * cp + 1] + d * sy;
    if (do_relu) { vx = fmaxf(vx, 0.f); vy = fmaxf(vy, 0.f); }
    if constexpr (sizeof(TOUT) == 2) {
      half2v o; o[0] = (_Float16)vx; o[1] = (_Float16)vy;
      *(half2v*)((_Float16*)Out + (size_t)r * 64 + 2 * cp) = o;
    } else {
      *(float2*)((float*)Out + (size_t)r * 64 + 2 * cp) = make_float2(vx, vy);
    }
  }
}

// ---- merged finish: blocks [0,ngemm) = propensity head (MFMA),
//      blocks [ngemm, ...) = outcome heads ----
__launch_bounds__(256)
__global__ void k_finish(const float* __restrict__ Z,
                         const float* __restrict__ Wp1, const float* __restrict__ bp1,
                         const float* __restrict__ Wp2, const float* __restrict__ bp2,
                         float* __restrict__ tprob,
                         const int* __restrict__ treat, const int* __restrict__ ctrl,
                         int T, int C,
                         const float* __restrict__ Wy1, const float* __restrict__ by1,
                         const float* __restrict__ Wy0, const float* __restrict__ by0,
                         float* __restrict__ y1, float* __restrict__ yc0,
                         float* __restrict__ y0, float* __restrict__ yc1,
                         int N, int ngemm) {
  int lane = threadIdx.x & 63;
  if ((int)blockIdx.x < ngemm) {
    int wv = threadIdx.x >> 6;
    int lo = lane & 15;
    int hi = lane >> 4;

    half8 bfrag[2][4];
#pragma unroll
    for (int ks = 0; ks < 2; ks++)
#pragma unroll
      for (int ct = 0; ct < 4; ct++)
#pragma unroll
        for (int j = 0; j < 8; j++)
          bfrag[ks][ct][j] = (_Float16)Wp1[(ks * 32 + hi * 8 + j) * 64 + ct * 16 + lo];

    int r0 = (blockIdx.x * 4 + wv) * 16;
    if (r0 >= N) return;

    f32x4 acc[4];
#pragma unroll
    for (int ct = 0; ct < 4; ct++)
#pragma unroll
      for (int j = 0; j < 4; j++) acc[ct][j] = 0.0f;

    int ar = min(r0 + lo, N - 1);
#pragma unroll
    for (int ks = 0; ks < 2; ks++) {
      const float4* p = (const float4*)(Z + (size_t)ar * 64 + ks * 32 + hi * 8);
      float4 u = p[0], v = p[1];
      half8 a;
      a[0] = (_Float16)u.x; a[1] = (_Float16)u.y; a[2] = (_Float16)u.z; a[3] = (_Float16)u.w;
      a[4] = (_Float16)v.x; a[5] = (_Float16)v.y; a[6] = (_Float16)v.z; a[7] = (_Float16)v.w;
#pragma unroll
      for (int ct = 0; ct < 4; ct++)
        acc[ct] = __builtin_amdgcn_mfma_f32_16x16x32_f16(a, bfrag[ks][ct], acc[ct], 0, 0, 0);
    }

    float w20[4], w21[4], b1v[4];
#pragma unroll
    for (int ct = 0; ct < 4; ct++) {
      int col = ct * 16 + lo;
      w20[ct] = Wp2[col * 2 + 0];
      w21[ct] = Wp2[col * 2 + 1];
      b1v[ct] = bp1[col];
    }
    float b20 = bp2[0], b21 = bp2[1];

#pragma unroll
    for (int j = 0; j < 4; j++) {
      float t0 = 0.f, t1 = 0.f;
#pragma unroll
      for (int ct = 0; ct < 4; ct++) {
        float h = lrelu(acc[ct][j] + b1v[ct]);
        t0 = fmaf(h, w20[ct], t0);
        t1 = fmaf(h, w21[ct], t1);
      }
#pragma unroll
      for (int m = 1; m <= 8; m <<= 1) {
        t0 += __shfl_xor(t0, m, 64);
        t1 += __shfl_xor(t1, m, 64);
      }
      int rr = r0 + hi * 4 + j;
      if (lo == 0 && rr < N) {
        tprob[(size_t)rr * 2 + 0] = lrelu(t0 + b20);
        tprob[(size_t)rr * 2 + 1] = lrelu(t1 + b21);
      }
    }
  } else {
    int wid = (((int)blockIdx.x - ngemm) * (int)blockDim.x + (int)threadIdx.x) >> 6;
    if (wid >= T + C) return;
    bool treated = wid < T;
    int idx = treated ? wid : wid - T;
    int row = treated ? treat[idx] : ctrl[idx];
    row = __builtin_amdgcn_readfirstlane(row);
    float v = Z[(size_t)row * 64 + lane];
    float s1 = wave_sum64(v * Wy1[lane]);
    float s0 = wave_sum64(v * Wy0[lane]);
    if (lane == 0) {
      float a1 = lrelu(s1 + by1[0]);
      float a0 = lrelu(s0 + by0[0]);
      if (treated) { y1[idx] = a1; yc0[idx] = a0; }
      else         { yc1[idx] = a1; y0[idx] = a0; }
    }
  }
}

extern "C" void kernel_launch(void* const* d_in, const int* in_sizes, int n_in,
                              void* d_out, int out_size, void* d_ws, size_t ws_size,
                              hipStream_t stream) {
  const int IN = 128, H = 64;
  const int N = in_sizes[0] / IN;
  const int E = in_sizes[1] / 2;
  const int T = in_sizes[2];
  const int C = in_sizes[3];
  const int nbuck = (N + 127) >> BSH;         // 782
  const int nblk = (E + CHUNK - 1) / CHUNK;   // 196

  const float* x    = (const float*)d_in[0];
  const int*   ei   = (const int*)d_in[1];
  const int*   src  = ei;
  const int*   dst  = ei + E;
  const int*   trt  = (const int*)d_in[2];
  const int*   ctl  = (const int*)d_in[3];
  const float* W1   = (const float*)d_in[4];
  const float* b1   = (const float*)d_in[5];
  const float* W2   = (const float*)d_in[6];
  const float* b2   = (const float*)d_in[7];
  const float* Wy1  = (const float*)d_in[8];
  const float* by1  = (const float*)d_in[9];
  const float* Wy0  = (const float*)d_in[10];
  const float* by0  = (const float*)d_in[11];
  const float* Wp1  = (const float*)d_in[12];
  const float* bp1  = (const float*)d_in[13];
  const float* Wp2  = (const float*)d_in[14];
  const float* bp2  = (const float*)d_in[15];

  float* out   = (float*)d_out;
  float* y1    = out;                          // [T]
  float* yc0   = out + T;                      // [T]
  float* y0    = out + 2 * T;                  // [C]
  float* yc1   = out + 2 * T + C;              // [C]
  float* tprob = out + 2 * T + 2 * C;          // [N,2]
  float* xZ2   = out + 2 * T + 2 * C + 2 * N;  // [N,64]

  // workspace layout (4-byte units)
  int* cur       = (int*)d_ws;                      // 1024 (zeroed by k_zero)
  int* offs      = cur + 1024;                      // N
  int* cnt       = offs + N;                        // N
  float* dinv    = (float*)(cnt + N);               // N
  unsigned int* pairs = (unsigned int*)(dinv + N);  // nbuck*CAP (slab; becomes slot)
  _Float16* g16  = (_Float16*)(pairs + (size_t)nbuck * CAP);  // (N+1)*64 halves
  _Float16* xZ1  = g16 + (size_t)(N + 1) * 64;                // N*64 halves

  k_zero<<<1, 1024, 0, stream>>>(cur);
  k_bin<<<nblk, 1024, 0, stream>>>(src, dst, E, nbuck, cur, pairs);
  k_sort<<<nbuck, 256, 0, stream>>>(pairs, cur, offs, cnt, dinv, N);

  const int ngemm = (N + 63) / 64;
  const int nagg = (int)(((size_t)N * 64 + 255) / 256);
  const int nheads = (int)(((size_t)(T + C) * 64 + 255) / 256);
  int* slot = (int*)pairs;  // sorted+padded src indices after k_sort

  // layer 1
  k_gemm_mfma<128, float><<<ngemm, 256, 0, stream>>>(x, W1, dinv, g16, N);
  k_agg<_Float16><<<nagg, 256, 0, stream>>>(g16, offs, cnt, slot, dinv, b1, xZ1, N, 1);

  // layer 2
  k_gemm_mfma<64, _Float16><<<ngemm, 256, 0, stream>>>(xZ1, W2, dinv, g16, N);
  k_agg<float><<<nagg, 256, 0, stream>>>(g16, offs, cnt, slot, dinv, b2, xZ2, N, 0);

  // heads (merged tprob + outcome)
  k_finish<<<ngemm + nheads, 256, 0, stream>>>(
      xZ2, Wp1, bp1, Wp2, bp2, tprob, trt, ctl, T, C,
      Wy1, by1, Wy0, by0, y1, yc0, y0, yc1, N, ngemm);
}

// Round 13
// 171.973 us; speedup vs baseline: 1.7172x; 1.0104x over previous
//
#include <hip/hip_runtime.h>
#include <math.h>

// ---------------------------------------------------------------------------
// CNE: 2-layer GCN (PyG GCNConv norm w/ self loops) + outcome/propensity heads
// N=100000, E=1600000, IN=128, H=64, T=C=20000.
//
// R13: single-pass register k_bin — each thread holds its 8 (src,dst) edges
// in VGPRs; hist + scatter from registers (edge list read once, 12.8MB vs
// 19.2MB, one latency pass instead of two). Everything else frozen (R12).
// ---------------------------------------------------------------------------

#define CHUNK 8192   // edges per binning block (8 per thread at 1024 thr)
#define BSH 7        // 128 dst nodes per bucket
#define CAP 4608     // slab capacity per bucket (padded sum <= ~4300)

typedef __attribute__((ext_vector_type(8))) _Float16 half8;
typedef __attribute__((ext_vector_type(2))) _Float16 half2v;
typedef __attribute__((ext_vector_type(4))) float f32x4;

__device__ __forceinline__ float lrelu(float x) { return x > 0.0f ? x : 0.01f * x; }

__device__ __forceinline__ float wave_sum64(float v) {
#pragma unroll
  for (int m = 32; m >= 1; m >>= 1) v += __shfl_xor(v, m, 64);
  return v;
}

// ---- zero the 1024-word bucket cursor array ----
__global__ void k_zero(int* __restrict__ cur) { cur[threadIdx.x] = 0; }

// ---- single-pass bin: edges in VGPRs -> LDS hist -> reserve -> scatter ----
__launch_bounds__(1024)
__global__ void k_bin(const int* __restrict__ src, const int* __restrict__ dst,
                      int E, int nbuck, int* __restrict__ cur,
                      unsigned int* __restrict__ pairs) {
  __shared__ int bh[1024];  // per-bucket count, then per-bucket cursor
  __shared__ int bb[1024];  // per-bucket reserved base
  int t = threadIdx.x;
  for (int i = t; i < nbuck; i += 1024) bh[i] = 0;
  __syncthreads();
  int e0 = blockIdx.x * CHUNK;

  int s[8], d[8];
#pragma unroll
  for (int u = 0; u < 8; u++) {
    int e = e0 + u * 1024 + t;  // coalesced
    bool ok = e < E;
    int ee = ok ? e : e0;
    s[u] = src[ee];
    d[u] = ok ? dst[ee] : -1;
  }
#pragma unroll
  for (int u = 0; u < 8; u++)
    if (d[u] >= 0) atomicAdd(&bh[d[u] >> BSH], 1);
  __syncthreads();
  for (int i = t; i < nbuck; i += 1024) {
    int c = bh[i];
    bb[i] = c ? atomicAdd(&cur[i], c) : 0;
  }
  __syncthreads();
  for (int i = t; i < nbuck; i += 1024) bh[i] = 0;  // reuse as intra-block cursor
  __syncthreads();
#pragma unroll
  for (int u = 0; u < 8; u++) {
    if (d[u] >= 0) {
      int b = d[u] >> BSH;
      int p = atomicAdd(&bh[b], 1);
      pairs[(size_t)b * CAP + bb[b] + p] =
          (unsigned int)s[u] | ((unsigned int)(d[u] & 127) << 20);
    }
  }
}

// ---- in-bucket sort (LDS-staged, in-place slab) -> padded per-node CSR ----
// Node lists padded to multiple of 32 with sentinel index N (zero G row).
__global__ void k_sort(unsigned int* __restrict__ pairs, const int* __restrict__ cur,
                       int* __restrict__ offs, int* __restrict__ cntout,
                       float* __restrict__ dinv, int N) {
  __shared__ unsigned int seg[CAP];
  __shared__ int hist[128];
  __shared__ int loc[128];
  __shared__ int lcur[128];
  __shared__ int pbase[128];
  int b = blockIdx.x, t = threadIdx.x;
  int c = cur[b];
  size_t base = (size_t)b * CAP;
  for (int i = t; i < c; i += 256) seg[i] = pairs[base + i];
  if (t < 128) hist[t] = 0;
  __syncthreads();  // all global reads of this block's slab segment done
  for (int i = t; i < c; i += 256) atomicAdd(&hist[seg[i] >> 20], 1);
  __syncthreads();
  if (t < 128) loc[t] = (hist[t] + 31) & ~31;  // padded length
  __syncthreads();
  for (int off = 1; off < 128; off <<= 1) {
    int u = (t >= off && t < 128) ? loc[t - off] : 0;
    __syncthreads();
    if (t < 128) loc[t] += u;
    __syncthreads();
  }
  if (t < 128) {
    int r32 = (hist[t] + 31) & ~31;
    int pex = loc[t] - r32;  // padded exclusive scan
    lcur[t] = pex;
    pbase[t] = pex;
    int node = (b << BSH) + t;
    if (node < N) {
      offs[node] = (int)base + pex;
      cntout[node] = r32;                         // padded count (agg loop bound)
      dinv[node] = rsqrtf((float)(hist[t] + 1));  // real degree for norm
    }
  }
  __syncthreads();
  for (int i = t; i < c; i += 256) {
    unsigned int p = seg[i];
    int d = (int)(p >> 20);
    int pos = atomicAdd(&lcur[d], 1);
    pairs[base + pos] = p & 0xFFFFFu;  // sorted src index
  }
  __syncthreads();
  if (t < 128) {
    int r32 = (hist[t] + 31) & ~31;
    for (int p = hist[t]; p < r32; p++) pairs[base + pbase[t] + p] = (unsigned int)N;
  }
}

// ---- MFMA GEMM: G16 = fp16( dinv * (X @ W) ); also zeroes G row N ----
template <int K, typename TIN>
__launch_bounds__(256)
__global__ void k_gemm_mfma(const TIN* __restrict__ X, const float* __restrict__ W,
                            const float* __restrict__ dinv, _Float16* __restrict__ G, int N) {
  constexpr int KST = K / 32;
  int lane = threadIdx.x & 63;
  int wv = threadIdx.x >> 6;
  int lo = lane & 15;   // A row / B,D col (within tile)
  int hi = lane >> 4;   // k-group for A/B; row-group for D

  if (blockIdx.x == 0 && threadIdx.x < 64) G[(size_t)N * 64 + threadIdx.x] = (_Float16)0.0f;

  half8 bfrag[KST][4];
#pragma unroll
  for (int ks = 0; ks < KST; ks++)
#pragma unroll
    for (int ct = 0; ct < 4; ct++)
#pragma unroll
      for (int j = 0; j < 8; j++)
        bfrag[ks][ct][j] = (_Float16)W[(ks * 32 + hi * 8 + j) * 64 + ct * 16 + lo];

  int r0 = (blockIdx.x * 4 + wv) * 16;
  if (r0 >= N) return;

  f32x4 acc[4];
#pragma unroll
  for (int ct = 0; ct < 4; ct++)
#pragma unroll
    for (int j = 0; j < 4; j++) acc[ct][j] = 0.0f;

  int ar = min(r0 + lo, N - 1);
#pragma unroll
  for (int ks = 0; ks < KST; ks++) {
    const TIN* ap = X + (size_t)ar * K + ks * 32 + hi * 8;
    half8 a;
    if constexpr (sizeof(TIN) == 4) {
      const float4* p = (const float4*)ap;
      float4 u = p[0], v = p[1];
      a[0] = (_Float16)u.x; a[1] = (_Float16)u.y; a[2] = (_Float16)u.z; a[3] = (_Float16)u.w;
      a[4] = (_Float16)v.x; a[5] = (_Float16)v.y; a[6] = (_Float16)v.z; a[7] = (_Float16)v.w;
    } else {
      a = *(const half8*)ap;
    }
#pragma unroll
    for (int ct = 0; ct < 4; ct++)
      acc[ct] = __builtin_amdgcn_mfma_f32_16x16x32_f16(a, bfrag[ks][ct], acc[ct], 0, 0, 0);
  }

  float dv[4];
#pragma unroll
  for (int j = 0; j < 4; j++) dv[j] = dinv[min(r0 + hi * 4 + j, N - 1)];
#pragma unroll
  for (int j = 0; j < 4; j++) {
    int rr = r0 + hi * 4 + j;
    if (rr < N) {
#pragma unroll
      for (int ct = 0; ct < 4; ct++)
        G[(size_t)rr * 64 + ct * 16 + lo] = (_Float16)(acc[ct][j] * dv[j]);
    }
  }
}

// ---- aggregation: wave per node, half2/lane, predication-free 32-window ----
template <typename TOUT>
__launch_bounds__(256)
__global__ void k_agg(const _Float16* __restrict__ G, const int* __restrict__ offs,
                      const int* __restrict__ count, const int* __restrict__ slot,
                      const float* __restrict__ dinv, const float* __restrict__ bias,
                      TOUT* __restrict__ Out, int N, int do_relu) {
  int lane = threadIdx.x & 63;
  int wid = (blockIdx.x * blockDim.x + threadIdx.x) >> 6;
  if (wid >= N) return;
  int r = __builtin_amdgcn_readfirstlane(wid);
  int cp = lane & 31;  // column pair: cols {2cp, 2cp+1}
  int rs = lane >> 5;  // row slot: even/odd edge
  int start = offs[r], cnt = count[r];  // cnt is multiple of 32 (padded)
  const _Float16* gp = G + 2 * cp;

  float sx = 0.f, sy = 0.f;
  if (rs == 0) {  // self row once
    half2v v = *(const half2v*)(gp + (size_t)r * 64);
    sx += (float)v[0]; sy += (float)v[1];
  }
  for (int j = 0; j < cnt; j += 32) {
    half2v v[16];
#pragma unroll
    for (int u = 0; u < 16; u++) {
      int e = slot[start + j + 2 * u + rs];
      v[u] = *(const half2v*)(gp + (size_t)e * 64);
    }
#pragma unroll
    for (int u = 0; u < 16; u++) { sx += (float)v[u][0]; sy += (float)v[u][1]; }
  }
  // merge even/odd edge halves
  sx += __shfl_xor(sx, 32, 64);
  sy += __shfl_xor(sy, 32, 64);

  if (rs == 0) {
    float d = dinv[r];
    float vx = bias[2 * cp] + d * sx;
    float vy = bias[2 * cp + 1] + d * sy;
    if (do_relu) { vx = fmaxf(vx, 0.f); vy = fmaxf(vy, 0.f); }
    if constexpr (sizeof(TOUT) == 2) {
      half2v o; o[0] = (_Float16)vx; o[1] = (_Float16)vy;
      *(half2v*)((_Float16*)Out + (size_t)r * 64 + 2 * cp) = o;
    } else {
      *(float2*)((float*)Out + (size_t)r * 64 + 2 * cp) = make_float2(vx, vy);
    }
  }
}

// ---- merged finish: blocks [0,ngemm) = propensity head (MFMA),
//      blocks [ngemm, ...) = outcome heads ----
__launch_bounds__(256)
__global__ void k_finish(const float* __restrict__ Z,
                         const float* __restrict__ Wp1, const float* __restrict__ bp1,
                         const float* __restrict__ Wp2, const float* __restrict__ bp2,
                         float* __restrict__ tprob,
                         const int* __restrict__ treat, const int* __restrict__ ctrl,
                         int T, int C,
                         const float* __restrict__ Wy1, const float* __restrict__ by1,
                         const float* __restrict__ Wy0, const float* __restrict__ by0,
                         float* __restrict__ y1, float* __restrict__ yc0,
                         float* __restrict__ y0, float* __restrict__ yc1,
                         int N, int ngemm) {
  int lane = threadIdx.x & 63;
  if ((int)blockIdx.x < ngemm) {
    int wv = threadIdx.x >> 6;
    int lo = lane & 15;
    int hi = lane >> 4;

    half8 bfrag[2][4];
#pragma unroll
    for (int ks = 0; ks < 2; ks++)
#pragma unroll
      for (int ct = 0; ct < 4; ct++)
#pragma unroll
        for (int j = 0; j < 8; j++)
          bfrag[ks][ct][j] = (_Float16)Wp1[(ks * 32 + hi * 8 + j) * 64 + ct * 16 + lo];

    int r0 = (blockIdx.x * 4 + wv) * 16;
    if (r0 >= N) return;

    f32x4 acc[4];
#pragma unroll
    for (int ct = 0; ct < 4; ct++)
#pragma unroll
      for (int j = 0; j < 4; j++) acc[ct][j] = 0.0f;

    int ar = min(r0 + lo, N - 1);
#pragma unroll
    for (int ks = 0; ks < 2; ks++) {
      const float4* p = (const float4*)(Z + (size_t)ar * 64 + ks * 32 + hi * 8);
      float4 u = p[0], v = p[1];
      half8 a;
      a[0] = (_Float16)u.x; a[1] = (_Float16)u.y; a[2] = (_Float16)u.z; a[3] = (_Float16)u.w;
      a[4] = (_Float16)v.x; a[5] = (_Float16)v.y; a[6] = (_Float16)v.z; a[7] = (_Float16)v.w;
#pragma unroll
      for (int ct = 0; ct < 4; ct++)
        acc[ct] = __builtin_amdgcn_mfma_f32_16x16x32_f16(a, bfrag[ks][ct], acc[ct], 0, 0, 0);
    }

    float w20[4], w21[4], b1v[4];
#pragma unroll
    for (int ct = 0; ct < 4; ct++) {
      int col = ct * 16 + lo;
      w20[ct] = Wp2[col * 2 + 0];
      w21[ct] = Wp2[col * 2 + 1];
      b1v[ct] = bp1[col];
    }
    float b20 = bp2[0], b21 = bp2[1];

#pragma unroll
    for (int j = 0; j < 4; j++) {
      float t0 = 0.f, t1 = 0.f;
#pragma unroll
      for (int ct = 0; ct < 4; ct++) {
        float h = lrelu(acc[ct][j] + b1v[ct]);
        t0 = fmaf(h, w20[ct], t0);
        t1 = fmaf(h, w21[ct], t1);
      }
#pragma unroll
      for (int m = 1; m <= 8; m <<= 1) {
        t0 += __shfl_xor(t0, m, 64);
        t1 += __shfl_xor(t1, m, 64);
      }
      int rr = r0 + hi * 4 + j;
      if (lo == 0 && rr < N) {
        tprob[(size_t)rr * 2 + 0] = lrelu(t0 + b20);
        tprob[(size_t)rr * 2 + 1] = lrelu(t1 + b21);
      }
    }
  } else {
    int wid = (((int)blockIdx.x - ngemm) * (int)blockDim.x + (int)threadIdx.x) >> 6;
    if (wid >= T + C) return;
    bool treated = wid < T;
    int idx = treated ? wid : wid - T;
    int row = treated ? treat[idx] : ctrl[idx];
    row = __builtin_amdgcn_readfirstlane(row);
    float v = Z[(size_t)row * 64 + lane];
    float s1 = wave_sum64(v * Wy1[lane]);
    float s0 = wave_sum64(v * Wy0[lane]);
    if (lane == 0) {
      float a1 = lrelu(s1 + by1[0]);
      float a0 = lrelu(s0 + by0[0]);
      if (treated) { y1[idx] = a1; yc0[idx] = a0; }
      else         { yc1[idx] = a1; y0[idx] = a0; }
    }
  }
}

extern "C" void kernel_launch(void* const* d_in, const int* in_sizes, int n_in,
                              void* d_out, int out_size, void* d_ws, size_t ws_size,
                              hipStream_t stream) {
  const int IN = 128, H = 64;
  const int N = in_sizes[0] / IN;
  const int E = in_sizes[1] / 2;
  const int T = in_sizes[2];
  const int C = in_sizes[3];
  const int nbuck = (N + 127) >> BSH;         // 782
  const int nblk = (E + CHUNK - 1) / CHUNK;   // 196

  const float* x    = (const float*)d_in[0];
  const int*   ei   = (const int*)d_in[1];
  const int*   src  = ei;
  const int*   dst  = ei + E;
  const int*   trt  = (const int*)d_in[2];
  const int*   ctl  = (const int*)d_in[3];
  const float* W1   = (const float*)d_in[4];
  const float* b1   = (const float*)d_in[5];
  const float* W2   = (const float*)d_in[6];
  const float* b2   = (const float*)d_in[7];
  const float* Wy1  = (const float*)d_in[8];
  const float* by1  = (const float*)d_in[9];
  const float* Wy0  = (const float*)d_in[10];
  const float* by0  = (const float*)d_in[11];
  const float* Wp1  = (const float*)d_in[12];
  const float* bp1  = (const float*)d_in[13];
  const float* Wp2  = (const float*)d_in[14];
  const float* bp2  = (const float*)d_in[15];

  float* out   = (float*)d_out;
  float* y1    = out;                          // [T]
  float* yc0   = out + T;                      // [T]
  float* y0    = out + 2 * T;                  // [C]
  float* yc1   = out + 2 * T + C;              // [C]
  float* tprob = out + 2 * T + 2 * C;          // [N,2]
  float* xZ2   = out + 2 * T + 2 * C + 2 * N;  // [N,64]

  // workspace layout (4-byte units)
  int* cur       = (int*)d_ws;                      // 1024 (zeroed by k_zero)
  int* offs      = cur + 1024;                      // N
  int* cnt       = offs + N;                        // N
  float* dinv    = (float*)(cnt + N);               // N
  unsigned int* pairs = (unsigned int*)(dinv + N);  // nbuck*CAP (slab; becomes slot)
  _Float16* g16  = (_Float16*)(pairs + (size_t)nbuck * CAP);  // (N+1)*64 halves
  _Float16* xZ1  = g16 + (size_t)(N + 1) * 64;                // N*64 halves

  k_zero<<<1, 1024, 0, stream>>>(cur);
  k_bin<<<nblk, 1024, 0, stream>>>(src, dst, E, nbuck, cur, pairs);
  k_sort<<<nbuck, 256, 0, stream>>>(pairs, cur, offs, cnt, dinv, N);

  const int ngemm = (N + 63) / 64;
  const int nagg = (int)(((size_t)N * 64 + 255) / 256);
  const int nheads = (int)(((size_t)(T + C) * 64 + 255) / 256);
  int* slot = (int*)pairs;  // sorted+padded src indices after k_sort

  // layer 1
  k_gemm_mfma<128, float><<<ngemm, 256, 0, stream>>>(x, W1, dinv, g16, N);
  k_agg<_Float16><<<nagg, 256, 0, stream>>>(g16, offs, cnt, slot, dinv, b1, xZ1, N, 1);

  // layer 2
  k_gemm_mfma<64, _Float16><<<ngemm, 256, 0, stream>>>(xZ1, W2, dinv, g16, N);
  k_agg<float><<<nagg, 256, 0, stream>>>(g16, offs, cnt, slot, dinv, b2, xZ2, N, 0);

  // heads (merged tprob + outcome)
  k_finish<<<ngemm + nheads, 256, 0, stream>>>(
      xZ2, Wp1, bp1, Wp2, bp2, tprob, trt, ctl, T, C,
      Wy1, by1, Wy0, by0, y1, yc0, y0, yc1, N, ngemm);
}